// Round 2
// baseline (3772.688 us; speedup 1.0000x reference)
//
#include <hip/hip_runtime.h>
#include <math.h>

// ---------------- problem constants ----------------
namespace {
constexpr int kB   = 4;
constexpr int kNG  = 100;
constexpr int kH1  = 112;            // feat H/W
constexpr int kH2  = 224;            // upscaled H/W
constexpr int kQ   = kH2 * kH2;      // 50176 queries per batch image

// workspace layout (bytes, all 256B-aligned). Per-batch buffers reused across
// the b=0..3 loop to keep peak scratch at ~129 MB (the all-batch coef/freq
// buffer alone would be 411 MB and risks exceeding ws_size -> GPU fault).
constexpr size_t SZ_H     = (size_t)kB * kH1 * kH1 * 64 * 4;     // 12,845,056  h (pixel-major, all b)
constexpr size_t SZ_GF1   = (size_t)64 * kH2 * kH2 * 4;          // 12,845,056  gfeat (one b)
constexpr size_t SZ_CF1   = (size_t)kH2 * kH2 * 512 * 4;         // 102,760,448 coef|freq (one b)
constexpr size_t OFF_H    = 0;
constexpr size_t OFF_GF   = OFF_H + SZ_H;
constexpr size_t OFF_CF   = OFF_GF + SZ_GF1;
constexpr size_t OFF_W1T  = OFF_CF + SZ_CF1;
constexpr size_t SZ_WT    = 256 * 256 * 4;
constexpr size_t OFF_W2T  = OFF_W1T + SZ_WT;
constexpr size_t OFF_WSUM = OFF_W2T + SZ_WT;
constexpr size_t OFF_WK   = OFF_WSUM + 1024;                     // 49*196 floats
// total ~129.0 MB
}  // namespace

// ---------------- tiny helpers ----------------
__global__ void k_init(float* wsums) {
  int t = threadIdx.x;
  if (t < 196) wsums[t] = 0.0f;
}

// W1t[k][j] = W1[j][k] ; same for W2  (tiny)
__global__ void k_transpose(const float* __restrict__ w1, const float* __restrict__ w2,
                            float* __restrict__ w1t, float* __restrict__ w2t) {
  int blk = blockIdx.x;
  const float* src = (blk < 256) ? w1 : w2;
  float* dst = (blk < 256) ? w1t : w2t;
  int k = blk & 255;
  int j = threadIdx.x;
  dst[k * 256 + j] = src[j * 256 + k];
}

// ---------------- 3x3 conv (pad=1), channel-major in, pixel-major out ----------------
// 64 co per block, 8x8 pixel tile, 4co x 4px register tile per thread.
// NB = number of batch images covered by this launch (input/output include that dim).
template <int IMG, int OSTRIDE, int NB, bool RELU>
__global__ __launch_bounds__(256) void k_conv3x3(
    const float* __restrict__ in,  // [NB][64][IMG][IMG]
    const float* __restrict__ wA,  // weights for co < 256, layout [co][ci][3][3]
    const float* __restrict__ bA,
    const float* __restrict__ wB,  // weights for co >= 256
    const float* __restrict__ bB,
    float* __restrict__ out)       // [NB][IMG][IMG][OSTRIDE]
{
  constexpr int TILES = IMG / 8;
  constexpr int PER_COG = NB * TILES * TILES;
  const int t = threadIdx.x;
  int blk = blockIdx.x;
  const int cog = blk / PER_COG;
  int rem = blk % PER_COG;
  const int b = rem / (TILES * TILES);
  rem %= TILES * TILES;
  const int py0 = (rem / TILES) * 8;
  const int px0 = (rem % TILES) * 8;
  const int cobase = cog * 64;
  const float* wsrc = (cobase < 256) ? (wA + (size_t)cobase * 576)
                                     : (wB + (size_t)(cobase - 256) * 576);
  const float* bsrc = (cobase < 256) ? (bA + cobase) : (bB + (cobase - 256));

  __shared__ float in_s[16 * 10 * 12];   // [ci][iy][ix] (ix padded 10->12)
  __shared__ float wl_s[16 * 9 * 65];    // [ci*9+k][co] (co padded 64->65)

  const int tc = t & 15;        // co quad selector
  const int tp = t >> 4;        // pixel selector
  const int rr = tp >> 1;       // row 0..7
  const int cq = (tp & 1) * 4;  // col base 0 or 4

  float acc[4][4];
#pragma unroll
  for (int c = 0; c < 4; ++c)
#pragma unroll
    for (int j = 0; j < 4; ++j) acc[c][j] = 0.0f;

  for (int ck = 0; ck < 4; ++ck) {
    const int ci0 = ck * 16;
    for (int idx = t; idx < 1600; idx += 256) {
      int ci = idx / 100;
      int r2 = idx % 100;
      int iy = r2 / 10, ix = r2 % 10;
      int gy = py0 - 1 + iy, gx = px0 - 1 + ix;
      float v = 0.0f;
      if (gy >= 0 && gy < IMG && gx >= 0 && gx < IMG)
        v = in[(((size_t)b * 64 + ci0 + ci) * IMG + gy) * IMG + gx];
      in_s[(ci * 10 + iy) * 12 + ix] = v;
    }
    for (int idx = t; idx < 9216; idx += 256) {
      int col = idx / 144;          // co within group
      int r2 = idx % 144;           // ci*9 + k
      wl_s[r2 * 65 + col] = wsrc[((size_t)col * 64 + ci0) * 9 + r2];
    }
    __syncthreads();
#pragma unroll 2
    for (int ci = 0; ci < 16; ++ci) {
#pragma unroll
      for (int ky = 0; ky < 3; ++ky) {
#pragma unroll
        for (int kx = 0; kx < 3; ++kx) {
          const int kk = ky * 3 + kx;
          const float* wp = &wl_s[(ci * 9 + kk) * 65 + tc * 4];
          const float* ip = &in_s[(ci * 10 + rr + ky) * 12 + cq + kx];
          float wv[4], iv[4];
#pragma unroll
          for (int c = 0; c < 4; ++c) wv[c] = wp[c];
#pragma unroll
          for (int j = 0; j < 4; ++j) iv[j] = ip[j];
#pragma unroll
          for (int c = 0; c < 4; ++c)
#pragma unroll
            for (int j = 0; j < 4; ++j) acc[c][j] += wv[c] * iv[j];
        }
      }
    }
    __syncthreads();
  }
  float bias[4];
#pragma unroll
  for (int c = 0; c < 4; ++c) bias[c] = bsrc[tc * 4 + c];
#pragma unroll
  for (int j = 0; j < 4; ++j) {
    const int y = py0 + rr;
    const int x = px0 + cq + j;
    size_t pix = ((size_t)b * IMG + y) * IMG + x;
    float4 v;
    v.x = acc[0][j] + bias[0];
    v.y = acc[1][j] + bias[1];
    v.z = acc[2][j] + bias[2];
    v.w = acc[3][j] + bias[3];
    if (RELU) {
      v.x = fmaxf(v.x, 0.0f); v.y = fmaxf(v.y, 0.0f);
      v.z = fmaxf(v.z, 0.0f); v.w = fmaxf(v.w, 0.0f);
    }
    *(float4*)&out[pix * OSTRIDE + cobase + tc * 4] = v;
  }
}

// ---------------- 1x1 conv + softmax over 100 groups + weighted sums -> wsums[4][49] ----------------
__global__ __launch_bounds__(256) void k_wavg(
    const float* __restrict__ h,   // [B][112][112][64] pixel-major
    const float* __restrict__ w2,  // [100][64]
    const float* __restrict__ b2,  // [100]
    const float* __restrict__ sx, const float* __restrict__ sy,
    const float* __restrict__ op, const float* __restrict__ rho,
    float* __restrict__ wsums)     // [4][49] (sum over all 50176 pixels)
{
  __shared__ float w2s[kNG * 64];
  __shared__ float prm[4 * kNG];
  __shared__ float b2s[kNG];
  __shared__ float pl[196];
  const int t = threadIdx.x;
  for (int i = t; i < kNG * 64; i += 256) w2s[i] = w2[i];
  if (t < kNG) {
    prm[t] = sx[t];
    prm[kNG + t] = sy[t];
    prm[2 * kNG + t] = op[t];
    prm[3 * kNG + t] = rho[t];
    b2s[t] = b2[t];
  }
  if (t < 196) pl[t] = 0.0f;
  __syncthreads();
  const int id = blockIdx.x * 256 + t;  // global pixel id (b,y,x row-major)
  float hreg[64];
  const float4* hp = (const float4*)(h + (size_t)id * 64);
#pragma unroll
  for (int i = 0; i < 16; ++i) {
    float4 v = hp[i];
    hreg[4 * i] = v.x; hreg[4 * i + 1] = v.y;
    hreg[4 * i + 2] = v.z; hreg[4 * i + 3] = v.w;
  }
  float S = 0, Sx = 0, Sy = 0, So = 0, Sr = 0;
  for (int g = 0; g < kNG; ++g) {
    float d = b2s[g];
    const float4* wp = (const float4*)(w2s + g * 64);
#pragma unroll
    for (int i = 0; i < 16; ++i) {
      float4 w = wp[i];
      d += hreg[4 * i] * w.x + hreg[4 * i + 1] * w.y +
           hreg[4 * i + 2] * w.z + hreg[4 * i + 3] * w.w;
    }
    float e = expf(d);  // logits are O(1); softmax without max-shift is safe in fp32
    S += e;
    Sx += e * prm[g];
    Sy += e * prm[kNG + g];
    So += e * prm[2 * kNG + g];
    Sr += e * prm[3 * kNG + g];
  }
  const int rem = id % (kH1 * kH1);
  const int p = ((rem / kH1) % 7) * 7 + ((rem % kH1) % 7);
  const float inv = 1.0f / S;
  atomicAdd(&pl[p], Sx * inv);
  atomicAdd(&pl[49 + p], Sy * inv);
  atomicAdd(&pl[98 + p], So * inv);
  atomicAdd(&pl[147 + p], Sr * inv);
  __syncthreads();
  if (t < 196) atomicAdd(&wsums[t], pl[t]);
}

// ---------------- build wk[p][h][w] = wop[p] * kt[p][h][w] ----------------
__global__ __launch_bounds__(256) void k_finalize(const float* __restrict__ wsums,
                                                  float* __restrict__ wk) {
  __shared__ float kern_s[49 * 25];
  __shared__ float wavg_s[196];
  const int t = threadIdx.x;
  if (t < 196) wavg_s[t] = wsums[t] * (1.0f / 1024.0f);  // mean over 4*16*16 patches
  __syncthreads();
  if (t < 49) {
    float wsx = wavg_s[t], wsy = wavg_s[49 + t], wr = wavg_s[147 + t];
    float c00 = wsx * wsx + 1e-5f;
    float c11 = wsy * wsy + 1e-5f;
    float c01 = wr * wsx * wsy;
    float det = c00 * c11 - c01 * c01;
    float i00 = c11 / det, i11 = c00 / det, i01 = -c01 / det;
    float nrm = 1.0f / (2.0f * 3.14159265358979323846f * sqrtf(det));
    float vals[25];
    float mx = -1e30f;
#pragma unroll
    for (int i = 0; i < 5; ++i) {
#pragma unroll
      for (int j = 0; j < 5; ++j) {
        float yv = -5.0f + 2.5f * (float)i;
        float xv = -5.0f + 2.5f * (float)j;
        float z = -0.5f * (i00 * xv * xv + 2.0f * i01 * xv * yv + i11 * yv * yv);
        float v = expf(z) * nrm;
        vals[i * 5 + j] = v;
        mx = fmaxf(mx, v);
      }
    }
#pragma unroll
    for (int k = 0; k < 25; ++k) kern_s[t * 25 + k] = vals[k] / mx;
  }
  __syncthreads();
  for (int idx = t; idx < 49 * 196; idx += 256) {
    const int p = idx / 196;
    const int hw = idx % 196;
    const int hh = hw / 14, ww = hw % 14;
    float txv = (0.5f - (float)(p / 7) / 7.0f) * 2.0f;
    float tyv = (0.5f - (float)(p % 7) / 7.0f) * 2.0f;
    float gxv = (-1.0f + (float)ww * (2.0f / 13.0f)) + txv;
    float gyv = (-1.0f + (float)hh * (2.0f / 13.0f)) + tyv;
    float pxv = (gxv + 1.0f) * 0.5f * 13.0f;
    float pyv = (gyv + 1.0f) * 0.5f * 13.0f;
    float x0f = floorf(pxv), y0f = floorf(pyv);
    int x0 = (int)x0f, y0 = (int)y0f;
    float wx = pxv - x0f, wy = pyv - y0f;
    auto samp = [&](int yi, int xi) -> float {
      // kpad nonzero only for yi,xi in [4,9)
      if (yi < 4 || yi >= 9 || xi < 4 || xi >= 9) return 0.0f;
      return kern_s[p * 25 + (yi - 4) * 5 + (xi - 4)];
    };
    float kt = samp(y0, x0) * (1.0f - wy) * (1.0f - wx) +
               samp(y0, x0 + 1) * (1.0f - wy) * wx +
               samp(y0 + 1, x0) * wy * (1.0f - wx) +
               samp(y0 + 1, x0 + 1) * wy * wx;
    wk[idx] = wavg_s[98 + p] * kt;  // * wop[p]
  }
}

// ---------------- splat (ONE batch image): gfeat[c][Y][X] = clip(sum_p feat*wk, 0, 1) ----------------
__global__ __launch_bounds__(256) void k_splat(const float* __restrict__ feat,  // [64][112][112] (pre-offset)
                                               const float* __restrict__ wk,    // [49][196]
                                               float* __restrict__ gfeat)       // [64][224][224]
{
  __shared__ float fs[64 * 49];
  __shared__ float wks[49 * 196];
  const int t = threadIdx.x;
  const int rem = blockIdx.x;   // 256 tiles
  const int ry = rem >> 4, rx = rem & 15;
  for (int idx = t; idx < 64 * 49; idx += 256) {
    int ci = idx / 49, p = idx % 49;
    int gy = ry * 7 + p / 7, gx = rx * 7 + p % 7;
    fs[idx] = feat[((size_t)ci * kH1 + gy) * kH1 + gx];
  }
  for (int idx = t; idx < 49 * 196; idx += 256) wks[idx] = wk[idx];
  __syncthreads();
  const int ci = t >> 2;
  const int s = t & 3;
  const int h0 = (s >> 1) * 7, w0 = (s & 1) * 7;
  float acc[49];
#pragma unroll
  for (int i = 0; i < 49; ++i) acc[i] = 0.0f;
  for (int p = 0; p < 49; ++p) {
    float f = fs[ci * 49 + p];
#pragma unroll
    for (int i = 0; i < 7; ++i)
#pragma unroll
      for (int j = 0; j < 7; ++j)
        acc[i * 7 + j] += f * wks[p * 196 + (h0 + i) * 14 + (w0 + j)];
  }
#pragma unroll
  for (int i = 0; i < 7; ++i)
#pragma unroll
    for (int j = 0; j < 7; ++j) {
      int Y = ry * 14 + h0 + i;
      int X = rx * 14 + w0 + j;
      float v = fminf(fmaxf(acc[i * 7 + j], 0.0f), 1.0f);
      gfeat[((size_t)ci * kH2 + Y) * kH2 + X] = v;
    }
}

// ---------------- fused query (ONE batch image): gather + basis + 3-layer MLP ----------------
__global__ __launch_bounds__(256) void k_query(
    const float* __restrict__ cf,     // [224][224][512] : coef(256)|freq(256), this batch
    const float* __restrict__ coord,  // [B][Q][2] (y,x) global
    const float* __restrict__ cell,   // [B][Q][2] global
    const float* __restrict__ phw,    // [128][2]
    const float* __restrict__ w1t,    // [256][256] k-major
    const float* __restrict__ b1,
    const float* __restrict__ w2t,
    const float* __restrict__ b2,
    const float* __restrict__ w3,     // [3][256]
    const float* __restrict__ b3,
    float* __restrict__ out,          // [B][Q][3] global
    int q_base)                       // b*kQ
{
  __shared__ float Xs[32 * 256];   // activations for 32 queries
  __shared__ float Wts[16 * 256];  // weight K-chunk
  const int t = threadIdx.x;
  const int q0 = q_base + blockIdx.x * 32;

  // ---- phase 1: gather + basis ----
  {
    const int tq = t >> 3, ts = t & 7;
    const int qg = q0 + tq;
    float gy = coord[(size_t)qg * 2 + 0];
    float gx = coord[(size_t)qg * 2 + 1];
    float fx = ((gx + 1.0f) * 224.0f - 1.0f) * 0.5f;
    float fy = ((gy + 1.0f) * 224.0f - 1.0f) * 0.5f;
    int ix = (int)rintf(fx);  // round-half-even == jnp.round
    int iy = (int)rintf(fy);
    bool ok = (ix >= 0) && (ix < 224) && (iy >= 0) && (iy < 224);
    int ixc = min(max(ix, 0), 223);
    int iyc = min(max(iy, 0), 223);
    float m = ok ? 1.0f : 0.0f;
    float qcy = ok ? (-1.0f + (1.0f / 224.0f) + (2.0f / 224.0f) * (float)iyc) : 0.0f;
    float qcx = ok ? (-1.0f + (1.0f / 224.0f) + (2.0f / 224.0f) * (float)ixc) : 0.0f;
    float rel0 = (gy - qcy) * 224.0f;
    float rel1 = (gx - qcx) * 224.0f;
    float rc0 = cell[(size_t)qg * 2 + 0] * 224.0f;
    float rc1 = cell[(size_t)qg * 2 + 1] * 224.0f;
    const float* base = cf + (((size_t)iyc * kH2 + ixc) * 512);
#pragma unroll
    for (int u = 0; u < 4; ++u) {
      const int k4 = ts * 16 + u * 4;
      float4 clo = *(const float4*)(base + k4);
      float4 chi = *(const float4*)(base + 128 + k4);
      float4 f0 = *(const float4*)(base + 256 + 2 * k4);
      float4 f1 = *(const float4*)(base + 256 + 2 * k4 + 4);
      float fr[8] = {f0.x, f0.y, f0.z, f0.w, f1.x, f1.y, f1.z, f1.w};
      float cl[4] = {clo.x, clo.y, clo.z, clo.w};
      float ch[4] = {chi.x, chi.y, chi.z, chi.w};
#pragma unroll
      for (int e = 0; e < 4; ++e) {
        const int k = k4 + e;
        float ph = rc0 * phw[2 * k] + rc1 * phw[2 * k + 1];
        float s = m * (fr[2 * e] * rel0 + fr[2 * e + 1] * rel1) + ph;
        float sv, cv;
        sincospif(s, &sv, &cv);  // sin(pi*s), cos(pi*s)
        Xs[tq * 256 + k] = m * cl[e] * cv;
        Xs[tq * 256 + 128 + k] = m * ch[e] * sv;
      }
    }
  }
  __syncthreads();

  // ---- phase 2: two 256x256 ReLU layers ----
  const int tj = t & 31, tq4 = t >> 5;
  const int jb = tj * 8;
#pragma unroll
  for (int layer = 0; layer < 2; ++layer) {
    const float* wt = layer ? w2t : w1t;
    const float* bs = layer ? b2 : b1;
    float acc[4][8];
#pragma unroll
    for (int i = 0; i < 4; ++i)
#pragma unroll
      for (int u = 0; u < 8; ++u) acc[i][u] = 0.0f;
    for (int kc = 0; kc < 16; ++kc) {
      const float4* src = (const float4*)(wt + (size_t)kc * 16 * 256);
      float4* dst = (float4*)Wts;
#pragma unroll
      for (int i = 0; i < 4; ++i) dst[t + i * 256] = src[t + i * 256];
      __syncthreads();
#pragma unroll
      for (int kk = 0; kk < 16; ++kk) {
        const int K = kc * 16 + kk;
        float xv[4];
#pragma unroll
        for (int i = 0; i < 4; ++i) xv[i] = Xs[(tq4 * 4 + i) * 256 + K];
        float4 wa = *(const float4*)&Wts[kk * 256 + jb];
        float4 wb = *(const float4*)&Wts[kk * 256 + jb + 4];
        float wv[8] = {wa.x, wa.y, wa.z, wa.w, wb.x, wb.y, wb.z, wb.w};
#pragma unroll
        for (int i = 0; i < 4; ++i)
#pragma unroll
          for (int u = 0; u < 8; ++u) acc[i][u] += xv[i] * wv[u];
      }
      __syncthreads();
    }
#pragma unroll
    for (int i = 0; i < 4; ++i)
#pragma unroll
      for (int u = 0; u < 8; ++u) {
        float v = acc[i][u] + bs[jb + u];
        Xs[(tq4 * 4 + i) * 256 + jb + u] = fmaxf(v, 0.0f);
      }
    __syncthreads();
  }

  // ---- phase 3: 3-wide output layer ----
  {
    const int ql = t >> 3, ts = t & 7;
    float c0 = 0, c1 = 0, c2 = 0;
    for (int k = ts; k < 256; k += 8) {
      float xv = Xs[ql * 256 + k];
      c0 += xv * w3[k];
      c1 += xv * w3[256 + k];
      c2 += xv * w3[512 + k];
    }
#pragma unroll
    for (int d = 4; d >= 1; d >>= 1) {
      c0 += __shfl_down(c0, d, 8);
      c1 += __shfl_down(c1, d, 8);
      c2 += __shfl_down(c2, d, 8);
    }
    if (ts == 0) {
      const int qg = q0 + ql;
      float* o = out + (size_t)qg * 3;
      o[0] = c0 + b3[0];
      o[1] = c1 + b3[1];
      o[2] = c2 + b3[2];
    }
  }
}

// ---------------- launch ----------------
extern "C" void kernel_launch(void* const* d_in, const int* in_sizes, int n_in,
                              void* d_out, int out_size, void* d_ws, size_t ws_size,
                              hipStream_t stream) {
  (void)in_sizes; (void)n_in; (void)out_size; (void)ws_size;
  const float* feat   = (const float*)d_in[0];
  const float* coord  = (const float*)d_in[1];
  const float* cell   = (const float*)d_in[2];
  const float* cls_w1 = (const float*)d_in[3];
  const float* cls_b1 = (const float*)d_in[4];
  const float* cls_w2 = (const float*)d_in[5];
  const float* cls_b2 = (const float*)d_in[6];
  const float* sigx   = (const float*)d_in[7];
  const float* sigy   = (const float*)d_in[8];
  const float* opac   = (const float*)d_in[9];
  const float* rho    = (const float*)d_in[10];
  const float* coef_w = (const float*)d_in[11];
  const float* coef_b = (const float*)d_in[12];
  const float* freq_w = (const float*)d_in[13];
  const float* freq_b = (const float*)d_in[14];
  const float* phw    = (const float*)d_in[15];
  const float* w1     = (const float*)d_in[16];
  const float* b1     = (const float*)d_in[17];
  const float* w2     = (const float*)d_in[18];
  const float* b2     = (const float*)d_in[19];
  const float* w3     = (const float*)d_in[20];
  const float* b3     = (const float*)d_in[21];

  char* ws = (char*)d_ws;
  float* h_buf = (float*)(ws + OFF_H);
  float* gf    = (float*)(ws + OFF_GF);   // one batch image, reused
  float* cfb   = (float*)(ws + OFF_CF);   // one batch image, reused
  float* w1t   = (float*)(ws + OFF_W1T);
  float* w2t   = (float*)(ws + OFF_W2T);
  float* wsums = (float*)(ws + OFF_WSUM);
  float* wk    = (float*)(ws + OFF_WK);
  float* outp  = (float*)d_out;

  hipLaunchKernelGGL(k_init, dim3(1), dim3(256), 0, stream, wsums);
  hipLaunchKernelGGL(k_transpose, dim3(512), dim3(256), 0, stream, w1, w2, w1t, w2t);
  // conv1: all 4 images, 64 out-ch -> h (pixel-major)
  hipLaunchKernelGGL((k_conv3x3<112, 64, 4, true>), dim3(784), dim3(256), 0, stream,
                     feat, cls_w1, cls_b1, cls_w1, cls_b1, h_buf);
  hipLaunchKernelGGL(k_wavg, dim3(196), dim3(256), 0, stream,
                     h_buf, cls_w2, cls_b2, sigx, sigy, opac, rho, wsums);
  hipLaunchKernelGGL(k_finalize, dim3(1), dim3(256), 0, stream, wsums, wk);

  // per-batch-image pipeline: splat -> conv2 -> query (buffers gf/cfb reused)
  for (int b = 0; b < kB; ++b) {
    const float* feat_b = feat + (size_t)b * 64 * kH1 * kH1;
    hipLaunchKernelGGL(k_splat, dim3(256), dim3(256), 0, stream, feat_b, wk, gf);
    hipLaunchKernelGGL((k_conv3x3<224, 512, 1, false>), dim3(6272), dim3(256), 0, stream,
                       gf, coef_w, coef_b, freq_w, freq_b, cfb);
    hipLaunchKernelGGL(k_query, dim3(1568), dim3(256), 0, stream,
                       cfb, coord, cell, phw, w1t, b1, w2t, b2, w3, b3, outp, b * kQ);
  }
}

// Round 3
// 2246.931 us; speedup vs baseline: 1.6790x; 1.6790x over previous
//
#include <hip/hip_runtime.h>
#include <math.h>

// ---------------- problem constants ----------------
namespace {
constexpr int kB   = 4;
constexpr int kNG  = 100;
constexpr int kH1  = 112;            // feat H/W
constexpr int kH2  = 224;            // upscaled H/W
constexpr int kQ   = kH2 * kH2;      // 50176 queries per batch image

// workspace layout (bytes). gf_hi/gf_lo overlap h (dead after k_wavg).
constexpr size_t OFF_H    = 0;                       // fp32 h [B][112][112][64] = 12,845,056
constexpr size_t OFF_GFH  = 0;                       // bf16 gfeat hi [224][224][64] = 6,422,528
constexpr size_t OFF_GFL  = 6422528;                 // bf16 gfeat lo
constexpr size_t OFF_CF   = 12845056;                // fp32 cf [224*224][512] = 102,760,448
constexpr size_t OFF_WPH  = OFF_CF + 102760448;      // W frag-order hi, 589,824
constexpr size_t OFF_WPL  = OFF_WPH + 589824;        // W frag-order lo
constexpr size_t OFF_W1T  = OFF_WPL + 589824;
constexpr size_t OFF_W2T  = OFF_W1T + 262144;
constexpr size_t OFF_WSUM = OFF_W2T + 262144;
constexpr size_t OFF_WK   = OFF_WSUM + 1024;
// total ~117.35 MB (round-1's 129.3 MB fit, so this is safe)
}  // namespace

using s8v = __attribute__((ext_vector_type(8))) short;   // 8 bf16 (4 VGPRs)
using f4v = __attribute__((ext_vector_type(4))) float;   // MFMA acc

__device__ __forceinline__ unsigned short f2bf(float f) {
  unsigned int u = __float_as_uint(f);
  unsigned int r = u + 0x7fffu + ((u >> 16) & 1u);   // round-nearest-even
  return (unsigned short)(r >> 16);
}
__device__ __forceinline__ float bf2f(unsigned short h) {
  return __uint_as_float((unsigned int)h << 16);
}

// ---------------- tiny helpers ----------------
__global__ void k_init(float* wsums) {
  int t = threadIdx.x;
  if (t < 196) wsums[t] = 0.0f;
}

__global__ void k_transpose(const float* __restrict__ w1, const float* __restrict__ w2,
                            float* __restrict__ w1t, float* __restrict__ w2t) {
  int blk = blockIdx.x;
  const float* src = (blk < 256) ? w1 : w2;
  float* dst = (blk < 256) ? w1t : w2t;
  int k = blk & 255;
  int j = threadIdx.x;
  dst[k * 256 + j] = src[j * 256 + k];
}

// Pack conv2 weights (coef 256 co + freq 256 co, K=576 as kk*64+ci) into
// MFMA B-fragment order, split bf16 hi/lo.
// frag f = (n16*18 + kstep); element = (f*64 + lane)*8 + j with
// lane = (kr>>3)*16 + (co&15), kr = k&31, j = kr&7.
__global__ void k_prepw(const float* __restrict__ cw, const float* __restrict__ fw,
                        unsigned short* __restrict__ wph, unsigned short* __restrict__ wpl) {
  int e = blockIdx.x * 256 + threadIdx.x;   // 512*576 = 294912
  int co = e / 576, k = e % 576;
  int ci = k & 63, kk = k >> 6;
  float v = (co < 256) ? cw[co * 576 + ci * 9 + kk] : fw[(co - 256) * 576 + ci * 9 + kk];
  unsigned short hi = f2bf(v);
  unsigned short lo = f2bf(v - bf2f(hi));
  int n16 = co >> 4, nl = co & 15;
  int kstep = k >> 5, kr = k & 31;
  int dst = ((n16 * 18 + kstep) * 64 + (kr >> 3) * 16 + nl) * 8 + (kr & 7);
  wph[dst] = hi;
  wpl[dst] = lo;
}

// ---------------- 3x3 conv (pad=1), channel-major in, pixel-major out (conv1 only) ----------------
template <int IMG, int OSTRIDE, int NB, bool RELU>
__global__ __launch_bounds__(256) void k_conv3x3(
    const float* __restrict__ in, const float* __restrict__ wA, const float* __restrict__ bA,
    const float* __restrict__ wB, const float* __restrict__ bB, float* __restrict__ out) {
  constexpr int TILES = IMG / 8;
  constexpr int PER_COG = NB * TILES * TILES;
  const int t = threadIdx.x;
  int blk = blockIdx.x;
  const int cog = blk / PER_COG;
  int rem = blk % PER_COG;
  const int b = rem / (TILES * TILES);
  rem %= TILES * TILES;
  const int py0 = (rem / TILES) * 8;
  const int px0 = (rem % TILES) * 8;
  const int cobase = cog * 64;
  const float* wsrc = (cobase < 256) ? (wA + (size_t)cobase * 576)
                                     : (wB + (size_t)(cobase - 256) * 576);
  const float* bsrc = (cobase < 256) ? (bA + cobase) : (bB + (cobase - 256));

  __shared__ float in_s[16 * 10 * 12];
  __shared__ float wl_s[16 * 9 * 65];

  const int tc = t & 15;
  const int tp = t >> 4;
  const int rr = tp >> 1;
  const int cq = (tp & 1) * 4;

  float acc[4][4];
#pragma unroll
  for (int c = 0; c < 4; ++c)
#pragma unroll
    for (int j = 0; j < 4; ++j) acc[c][j] = 0.0f;

  for (int ck = 0; ck < 4; ++ck) {
    const int ci0 = ck * 16;
    for (int idx = t; idx < 1600; idx += 256) {
      int ci = idx / 100;
      int r2 = idx % 100;
      int iy = r2 / 10, ix = r2 % 10;
      int gy = py0 - 1 + iy, gx = px0 - 1 + ix;
      float v = 0.0f;
      if (gy >= 0 && gy < IMG && gx >= 0 && gx < IMG)
        v = in[(((size_t)b * 64 + ci0 + ci) * IMG + gy) * IMG + gx];
      in_s[(ci * 10 + iy) * 12 + ix] = v;
    }
    for (int idx = t; idx < 9216; idx += 256) {
      int col = idx / 144;
      int r2 = idx % 144;
      wl_s[r2 * 65 + col] = wsrc[((size_t)col * 64 + ci0) * 9 + r2];
    }
    __syncthreads();
#pragma unroll 2
    for (int ci = 0; ci < 16; ++ci) {
#pragma unroll
      for (int ky = 0; ky < 3; ++ky) {
#pragma unroll
        for (int kx = 0; kx < 3; ++kx) {
          const int kk = ky * 3 + kx;
          const float* wp = &wl_s[(ci * 9 + kk) * 65 + tc * 4];
          const float* ip = &in_s[(ci * 10 + rr + ky) * 12 + cq + kx];
          float wv[4], iv[4];
#pragma unroll
          for (int c = 0; c < 4; ++c) wv[c] = wp[c];
#pragma unroll
          for (int j = 0; j < 4; ++j) iv[j] = ip[j];
#pragma unroll
          for (int c = 0; c < 4; ++c)
#pragma unroll
            for (int j = 0; j < 4; ++j) acc[c][j] += wv[c] * iv[j];
        }
      }
    }
    __syncthreads();
  }
  float bias[4];
#pragma unroll
  for (int c = 0; c < 4; ++c) bias[c] = bsrc[tc * 4 + c];
#pragma unroll
  for (int j = 0; j < 4; ++j) {
    const int y = py0 + rr;
    const int x = px0 + cq + j;
    size_t pix = ((size_t)b * IMG + y) * IMG + x;
    float4 v;
    v.x = acc[0][j] + bias[0];
    v.y = acc[1][j] + bias[1];
    v.z = acc[2][j] + bias[2];
    v.w = acc[3][j] + bias[3];
    if (RELU) {
      v.x = fmaxf(v.x, 0.0f); v.y = fmaxf(v.y, 0.0f);
      v.z = fmaxf(v.z, 0.0f); v.w = fmaxf(v.w, 0.0f);
    }
    *(float4*)&out[pix * OSTRIDE + cobase + tc * 4] = v;
  }
}

// ---------------- 1x1 conv + softmax + weighted sums -> wsums[4][49] ----------------
__global__ __launch_bounds__(256) void k_wavg(
    const float* __restrict__ h, const float* __restrict__ w2, const float* __restrict__ b2,
    const float* __restrict__ sx, const float* __restrict__ sy,
    const float* __restrict__ op, const float* __restrict__ rho,
    float* __restrict__ wsums) {
  __shared__ float w2s[kNG * 64];
  __shared__ float prm[4 * kNG];
  __shared__ float b2s[kNG];
  __shared__ float pl[196];
  const int t = threadIdx.x;
  for (int i = t; i < kNG * 64; i += 256) w2s[i] = w2[i];
  if (t < kNG) {
    prm[t] = sx[t];
    prm[kNG + t] = sy[t];
    prm[2 * kNG + t] = op[t];
    prm[3 * kNG + t] = rho[t];
    b2s[t] = b2[t];
  }
  if (t < 196) pl[t] = 0.0f;
  __syncthreads();
  const int id = blockIdx.x * 256 + t;
  float hreg[64];
  const float4* hp = (const float4*)(h + (size_t)id * 64);
#pragma unroll
  for (int i = 0; i < 16; ++i) {
    float4 v = hp[i];
    hreg[4 * i] = v.x; hreg[4 * i + 1] = v.y;
    hreg[4 * i + 2] = v.z; hreg[4 * i + 3] = v.w;
  }
  float S = 0, Sx = 0, Sy = 0, So = 0, Sr = 0;
  for (int g = 0; g < kNG; ++g) {
    float d = b2s[g];
    const float4* wp = (const float4*)(w2s + g * 64);
#pragma unroll
    for (int i = 0; i < 16; ++i) {
      float4 w = wp[i];
      d += hreg[4 * i] * w.x + hreg[4 * i + 1] * w.y +
           hreg[4 * i + 2] * w.z + hreg[4 * i + 3] * w.w;
    }
    float e = expf(d);
    S += e;
    Sx += e * prm[g];
    Sy += e * prm[kNG + g];
    So += e * prm[2 * kNG + g];
    Sr += e * prm[3 * kNG + g];
  }
  const int rem = id % (kH1 * kH1);
  const int p = ((rem / kH1) % 7) * 7 + ((rem % kH1) % 7);
  const float inv = 1.0f / S;
  atomicAdd(&pl[p], Sx * inv);
  atomicAdd(&pl[49 + p], Sy * inv);
  atomicAdd(&pl[98 + p], So * inv);
  atomicAdd(&pl[147 + p], Sr * inv);
  __syncthreads();
  if (t < 196) atomicAdd(&wsums[t], pl[t]);
}

// ---------------- build wk[p][h][w] ----------------
__global__ __launch_bounds__(256) void k_finalize(const float* __restrict__ wsums,
                                                  float* __restrict__ wk) {
  __shared__ float kern_s[49 * 25];
  __shared__ float wavg_s[196];
  const int t = threadIdx.x;
  if (t < 196) wavg_s[t] = wsums[t] * (1.0f / 1024.0f);
  __syncthreads();
  if (t < 49) {
    float wsx = wavg_s[t], wsy = wavg_s[49 + t], wr = wavg_s[147 + t];
    float c00 = wsx * wsx + 1e-5f;
    float c11 = wsy * wsy + 1e-5f;
    float c01 = wr * wsx * wsy;
    float det = c00 * c11 - c01 * c01;
    float i00 = c11 / det, i11 = c00 / det, i01 = -c01 / det;
    float nrm = 1.0f / (2.0f * 3.14159265358979323846f * sqrtf(det));
    float vals[25];
    float mx = -1e30f;
#pragma unroll
    for (int i = 0; i < 5; ++i) {
#pragma unroll
      for (int j = 0; j < 5; ++j) {
        float yv = -5.0f + 2.5f * (float)i;
        float xv = -5.0f + 2.5f * (float)j;
        float z = -0.5f * (i00 * xv * xv + 2.0f * i01 * xv * yv + i11 * yv * yv);
        float v = expf(z) * nrm;
        vals[i * 5 + j] = v;
        mx = fmaxf(mx, v);
      }
    }
#pragma unroll
    for (int k = 0; k < 25; ++k) kern_s[t * 25 + k] = vals[k] / mx;
  }
  __syncthreads();
  for (int idx = t; idx < 49 * 196; idx += 256) {
    const int p = idx / 196;
    const int hw = idx % 196;
    const int hh = hw / 14, ww = hw % 14;
    float txv = (0.5f - (float)(p / 7) / 7.0f) * 2.0f;
    float tyv = (0.5f - (float)(p % 7) / 7.0f) * 2.0f;
    float gxv = (-1.0f + (float)ww * (2.0f / 13.0f)) + txv;
    float gyv = (-1.0f + (float)hh * (2.0f / 13.0f)) + tyv;
    float pxv = (gxv + 1.0f) * 0.5f * 13.0f;
    float pyv = (gyv + 1.0f) * 0.5f * 13.0f;
    float x0f = floorf(pxv), y0f = floorf(pyv);
    int x0 = (int)x0f, y0 = (int)y0f;
    float wx = pxv - x0f, wy = pyv - y0f;
    auto samp = [&](int yi, int xi) -> float {
      if (yi < 4 || yi >= 9 || xi < 4 || xi >= 9) return 0.0f;
      return kern_s[p * 25 + (yi - 4) * 5 + (xi - 4)];
    };
    float kt = samp(y0, x0) * (1.0f - wy) * (1.0f - wx) +
               samp(y0, x0 + 1) * (1.0f - wy) * wx +
               samp(y0 + 1, x0) * wy * (1.0f - wx) +
               samp(y0 + 1, x0 + 1) * wy * wx;
    wk[idx] = wavg_s[98 + p] * kt;
  }
}

// ---------------- splat (ONE image) -> pixel-major bf16 hi/lo gfeat ----------------
__global__ __launch_bounds__(256) void k_splat(const float* __restrict__ feat,  // [64][112][112]
                                               const float* __restrict__ wk,    // [49][196]
                                               unsigned short* __restrict__ gfh, // [224*224][64]
                                               unsigned short* __restrict__ gfl) {
  __shared__ float fs[64 * 49];
  __shared__ float wks[49 * 196];
  const int t = threadIdx.x;
  const int rem = blockIdx.x;   // 256 tiles
  const int ry = rem >> 4, rx = rem & 15;
  for (int idx = t; idx < 64 * 49; idx += 256) {
    int ci = idx / 49, p = idx % 49;
    int gy = ry * 7 + p / 7, gx = rx * 7 + p % 7;
    fs[idx] = feat[((size_t)ci * kH1 + gy) * kH1 + gx];
  }
  for (int idx = t; idx < 49 * 196; idx += 256) wks[idx] = wk[idx];
  __syncthreads();
  const int ci = t & 63;        // lane-contiguous channel -> coalesced bf16 stores
  const int s = t >> 6;         // quadrant per wave
  const int h0 = (s >> 1) * 7, w0 = (s & 1) * 7;
  float acc[49];
#pragma unroll
  for (int i = 0; i < 49; ++i) acc[i] = 0.0f;
  for (int p = 0; p < 49; ++p) {
    float f = fs[ci * 49 + p];
#pragma unroll
    for (int i = 0; i < 7; ++i)
#pragma unroll
      for (int j = 0; j < 7; ++j)
        acc[i * 7 + j] += f * wks[p * 196 + (h0 + i) * 14 + (w0 + j)];
  }
#pragma unroll
  for (int i = 0; i < 7; ++i)
#pragma unroll
    for (int j = 0; j < 7; ++j) {
      int Y = ry * 14 + h0 + i;
      int X = rx * 14 + w0 + j;
      float v = fminf(fmaxf(acc[i * 7 + j], 0.0f), 1.0f);
      unsigned short hi = f2bf(v);
      unsigned short lo = f2bf(v - bf2f(hi));
      size_t o = ((size_t)Y * kH2 + X) * 64 + ci;
      gfh[o] = hi;
      gfl[o] = lo;
    }
}

// ---------------- conv2 as bf16x3 MFMA implicit GEMM (ONE image) ----------------
// Block: M=128 pixels (16x8 tile) x N=256 co; 4 waves, each M=128 x N=64.
// A (gfeat hi/lo) staged in LDS; B (weights) loaded frag-direct from L2.
__global__ __launch_bounds__(256, 2) void k_conv2_mfma(
    const unsigned short* __restrict__ gfh,  // [224*224][64] bf16 hi
    const unsigned short* __restrict__ gfl,  // lo
    const unsigned short* __restrict__ wph,  // frag-order W hi
    const unsigned short* __restrict__ wpl,  // frag-order W lo
    const float* __restrict__ coef_b, const float* __restrict__ freq_b,
    float* __restrict__ outp)                // [224*224][512]
{
  // LDS: 2 planes x 180 halo pixels x 72 halves (64 data + 8 pad) = 51,840 B
  __shared__ __attribute__((aligned(16))) char Asb[2 * 180 * 144];
  const int t = threadIdx.x;
  const int blk = blockIdx.x;       // 392 Mtiles * 2 Nhalves
  const int nb = blk & 1;
  const int mt = blk >> 1;
  const int ty = mt / 28, tx = mt % 28;
  const int py0 = ty * 16, px0 = tx * 8;

  // ---- stage A halo tile (18x10 pixels, hi+lo) ----
  for (int idx = t; idx < 2880; idx += 256) {
    int plane = idx >= 1440;
    int r2 = plane ? idx - 1440 : idx;
    int p = r2 >> 3, c8 = r2 & 7;
    int pr = p / 10, pc = p % 10;
    int gy = py0 - 1 + pr, gx = px0 - 1 + pc;
    uint4 u = make_uint4(0u, 0u, 0u, 0u);
    if (gy >= 0 && gy < kH2 && gx >= 0 && gx < kH2) {
      const unsigned short* src = (plane ? gfl : gfh) + ((size_t)(gy * kH2 + gx)) * 64 + c8 * 8;
      u = *(const uint4*)src;
    }
    *(uint4*)(Asb + plane * 25920 + p * 144 + c8 * 16) = u;
  }
  __syncthreads();

  const int w = t >> 6, lane = t & 63;
  const int quad = lane >> 4, ml = lane & 15;
  // per-lane A base: pixel (ml>>3, ml&7) within the M-tile, + k-quad offset
  const int abase = (((ml >> 3) * 10) + (ml & 7)) * 144 + quad * 16;
  const int n16base = nb * 16 + w * 4;
  const unsigned int bvoff = (unsigned int)lane * 16u;

  f4v acc[8][4];
#pragma unroll
  for (int i = 0; i < 8; ++i)
#pragma unroll
    for (int j = 0; j < 4; ++j) acc[i][j] = (f4v){0.0f, 0.0f, 0.0f, 0.0f};

#pragma unroll
  for (int kk = 0; kk < 9; ++kk) {
    const int ky = kk / 3, kx = kk % 3;
#pragma unroll
    for (int cs = 0; cs < 2; ++cs) {
      const int kstep = kk * 2 + cs;
      s8v Bh[4], Bl[4];
#pragma unroll
      for (int j = 0; j < 4; ++j) {
        unsigned int off = ((unsigned int)(n16base + j) * 18u + (unsigned int)kstep) * 1024u + bvoff;
        Bh[j] = *(const s8v*)((const char*)wph + off);
        Bl[j] = *(const s8v*)((const char*)wpl + off);
      }
#pragma unroll
      for (int i = 0; i < 8; ++i) {
        const int aoff = ((2 * i + ky) * 10 + kx) * 144 + cs * 64 + abase;
        s8v Ah = *(const s8v*)(Asb + aoff);
        s8v Al = *(const s8v*)(Asb + 25920 + aoff);
#pragma unroll
        for (int j = 0; j < 4; ++j) {
          acc[i][j] = __builtin_amdgcn_mfma_f32_16x16x32_bf16(Ah, Bh[j], acc[i][j], 0, 0, 0);
          acc[i][j] = __builtin_amdgcn_mfma_f32_16x16x32_bf16(Al, Bh[j], acc[i][j], 0, 0, 0);
          acc[i][j] = __builtin_amdgcn_mfma_f32_16x16x32_bf16(Ah, Bl[j], acc[i][j], 0, 0, 0);
        }
      }
    }
  }

  // ---- epilogue: D frag col=lane&15 (n), row=quad*4+reg (m) ----
  const int cobase = nb * 256 + w * 64;
  float bj[4];
#pragma unroll
  for (int j = 0; j < 4; ++j) {
    int co = cobase + j * 16 + ml;
    bj[j] = (co < 256) ? coef_b[co] : freq_b[co - 256];
  }
#pragma unroll
  for (int i = 0; i < 8; ++i) {
#pragma unroll
    for (int reg = 0; reg < 4; ++reg) {
      int m = i * 16 + quad * 4 + reg;
      int Y = py0 + (m >> 3), X = px0 + (m & 7);
      float* o = outp + ((size_t)(Y * kH2 + X)) * 512 + cobase + ml;
#pragma unroll
      for (int j = 0; j < 4; ++j) o[j * 16] = acc[i][j][reg] + bj[j];
    }
  }
}

// ---------------- fused query (ONE image): gather + basis + 3-layer MLP ----------------
__global__ __launch_bounds__(256) void k_query(
    const float* __restrict__ cf, const float* __restrict__ coord,
    const float* __restrict__ cell, const float* __restrict__ phw,
    const float* __restrict__ w1t, const float* __restrict__ b1,
    const float* __restrict__ w2t, const float* __restrict__ b2,
    const float* __restrict__ w3, const float* __restrict__ b3,
    float* __restrict__ out, int q_base) {
  __shared__ float Xs[32 * 256];
  __shared__ float Wts[16 * 256];
  const int t = threadIdx.x;
  const int q0 = q_base + blockIdx.x * 32;

  {
    const int tq = t >> 3, ts = t & 7;
    const int qg = q0 + tq;
    float gy = coord[(size_t)qg * 2 + 0];
    float gx = coord[(size_t)qg * 2 + 1];
    float fx = ((gx + 1.0f) * 224.0f - 1.0f) * 0.5f;
    float fy = ((gy + 1.0f) * 224.0f - 1.0f) * 0.5f;
    int ix = (int)rintf(fx);
    int iy = (int)rintf(fy);
    bool ok = (ix >= 0) && (ix < 224) && (iy >= 0) && (iy < 224);
    int ixc = min(max(ix, 0), 223);
    int iyc = min(max(iy, 0), 223);
    float m = ok ? 1.0f : 0.0f;
    float qcy = ok ? (-1.0f + (1.0f / 224.0f) + (2.0f / 224.0f) * (float)iyc) : 0.0f;
    float qcx = ok ? (-1.0f + (1.0f / 224.0f) + (2.0f / 224.0f) * (float)ixc) : 0.0f;
    float rel0 = (gy - qcy) * 224.0f;
    float rel1 = (gx - qcx) * 224.0f;
    float rc0 = cell[(size_t)qg * 2 + 0] * 224.0f;
    float rc1 = cell[(size_t)qg * 2 + 1] * 224.0f;
    const float* base = cf + (((size_t)iyc * kH2 + ixc) * 512);
#pragma unroll
    for (int u = 0; u < 4; ++u) {
      const int k4 = ts * 16 + u * 4;
      float4 clo = *(const float4*)(base + k4);
      float4 chi = *(const float4*)(base + 128 + k4);
      float4 f0 = *(const float4*)(base + 256 + 2 * k4);
      float4 f1 = *(const float4*)(base + 256 + 2 * k4 + 4);
      float fr[8] = {f0.x, f0.y, f0.z, f0.w, f1.x, f1.y, f1.z, f1.w};
      float cl[4] = {clo.x, clo.y, clo.z, clo.w};
      float ch[4] = {chi.x, chi.y, chi.z, chi.w};
#pragma unroll
      for (int e = 0; e < 4; ++e) {
        const int k = k4 + e;
        float ph = rc0 * phw[2 * k] + rc1 * phw[2 * k + 1];
        float s = m * (fr[2 * e] * rel0 + fr[2 * e + 1] * rel1) + ph;
        float sv, cv;
        sincospif(s, &sv, &cv);
        Xs[tq * 256 + k] = m * cl[e] * cv;
        Xs[tq * 256 + 128 + k] = m * ch[e] * sv;
      }
    }
  }
  __syncthreads();

  const int tj = t & 31, tq4 = t >> 5;
  const int jb = tj * 8;
#pragma unroll
  for (int layer = 0; layer < 2; ++layer) {
    const float* wt = layer ? w2t : w1t;
    const float* bs = layer ? b2 : b1;
    float acc[4][8];
#pragma unroll
    for (int i = 0; i < 4; ++i)
#pragma unroll
      for (int u = 0; u < 8; ++u) acc[i][u] = 0.0f;
    for (int kc = 0; kc < 16; ++kc) {
      const float4* src = (const float4*)(wt + (size_t)kc * 16 * 256);
      float4* dst = (float4*)Wts;
#pragma unroll
      for (int i = 0; i < 4; ++i) dst[t + i * 256] = src[t + i * 256];
      __syncthreads();
#pragma unroll
      for (int kkk = 0; kkk < 16; ++kkk) {
        const int K = kc * 16 + kkk;
        float xv[4];
#pragma unroll
        for (int i = 0; i < 4; ++i) xv[i] = Xs[(tq4 * 4 + i) * 256 + K];
        float4 wa = *(const float4*)&Wts[kkk * 256 + jb];
        float4 wb = *(const float4*)&Wts[kkk * 256 + jb + 4];
        float wv[8] = {wa.x, wa.y, wa.z, wa.w, wb.x, wb.y, wb.z, wb.w};
#pragma unroll
        for (int i = 0; i < 4; ++i)
#pragma unroll
          for (int u = 0; u < 8; ++u) acc[i][u] += xv[i] * wv[u];
      }
      __syncthreads();
    }
#pragma unroll
    for (int i = 0; i < 4; ++i)
#pragma unroll
      for (int u = 0; u < 8; ++u) {
        float v = acc[i][u] + bs[jb + u];
        Xs[(tq4 * 4 + i) * 256 + jb + u] = fmaxf(v, 0.0f);
      }
    __syncthreads();
  }

  {
    const int ql = t >> 3, ts = t & 7;
    float c0 = 0, c1 = 0, c2 = 0;
    for (int k = ts; k < 256; k += 8) {
      float xv = Xs[ql * 256 + k];
      c0 += xv * w3[k];
      c1 += xv * w3[256 + k];
      c2 += xv * w3[512 + k];
    }
#pragma unroll
    for (int d = 4; d >= 1; d >>= 1) {
      c0 += __shfl_down(c0, d, 8);
      c1 += __shfl_down(c1, d, 8);
      c2 += __shfl_down(c2, d, 8);
    }
    if (ts == 0) {
      const int qg = q0 + ql;
      float* o = out + (size_t)qg * 3;
      o[0] = c0 + b3[0];
      o[1] = c1 + b3[1];
      o[2] = c2 + b3[2];
    }
  }
}

// ---------------- launch ----------------
extern "C" void kernel_launch(void* const* d_in, const int* in_sizes, int n_in,
                              void* d_out, int out_size, void* d_ws, size_t ws_size,
                              hipStream_t stream) {
  (void)in_sizes; (void)n_in; (void)out_size; (void)ws_size;
  const float* feat   = (const float*)d_in[0];
  const float* coord  = (const float*)d_in[1];
  const float* cell   = (const float*)d_in[2];
  const float* cls_w1 = (const float*)d_in[3];
  const float* cls_b1 = (const float*)d_in[4];
  const float* cls_w2 = (const float*)d_in[5];
  const float* cls_b2 = (const float*)d_in[6];
  const float* sigx   = (const float*)d_in[7];
  const float* sigy   = (const float*)d_in[8];
  const float* opac   = (const float*)d_in[9];
  const float* rho    = (const float*)d_in[10];
  const float* coef_w = (const float*)d_in[11];
  const float* coef_b = (const float*)d_in[12];
  const float* freq_w = (const float*)d_in[13];
  const float* freq_b = (const float*)d_in[14];
  const float* phw    = (const float*)d_in[15];
  const float* w1     = (const float*)d_in[16];
  const float* b1     = (const float*)d_in[17];
  const float* w2     = (const float*)d_in[18];
  const float* b2     = (const float*)d_in[19];
  const float* w3     = (const float*)d_in[20];
  const float* b3     = (const float*)d_in[21];

  char* ws = (char*)d_ws;
  float* h_buf = (float*)(ws + OFF_H);
  unsigned short* gfh = (unsigned short*)(ws + OFF_GFH);   // overlaps h (dead)
  unsigned short* gfl = (unsigned short*)(ws + OFF_GFL);
  float* cfb   = (float*)(ws + OFF_CF);
  unsigned short* wph = (unsigned short*)(ws + OFF_WPH);
  unsigned short* wpl = (unsigned short*)(ws + OFF_WPL);
  float* w1t   = (float*)(ws + OFF_W1T);
  float* w2t   = (float*)(ws + OFF_W2T);
  float* wsums = (float*)(ws + OFF_WSUM);
  float* wk    = (float*)(ws + OFF_WK);
  float* outp  = (float*)d_out;

  hipLaunchKernelGGL(k_init, dim3(1), dim3(256), 0, stream, wsums);
  hipLaunchKernelGGL(k_transpose, dim3(512), dim3(256), 0, stream, w1, w2, w1t, w2t);
  hipLaunchKernelGGL(k_prepw, dim3(1152), dim3(256), 0, stream, coef_w, freq_w, wph, wpl);
  hipLaunchKernelGGL((k_conv3x3<112, 64, 4, true>), dim3(784), dim3(256), 0, stream,
                     feat, cls_w1, cls_b1, cls_w1, cls_b1, h_buf);
  hipLaunchKernelGGL(k_wavg, dim3(196), dim3(256), 0, stream,
                     h_buf, cls_w2, cls_b2, sigx, sigy, opac, rho, wsums);
  hipLaunchKernelGGL(k_finalize, dim3(1), dim3(256), 0, stream, wsums, wk);

  for (int b = 0; b < kB; ++b) {
    const float* feat_b = feat + (size_t)b * 64 * kH1 * kH1;
    hipLaunchKernelGGL(k_splat, dim3(256), dim3(256), 0, stream, feat_b, wk, gfh, gfl);
    hipLaunchKernelGGL(k_conv2_mfma, dim3(784), dim3(256), 0, stream,
                       gfh, gfl, wph, wpl, coef_b, freq_b, cfb);
    hipLaunchKernelGGL(k_query, dim3(1568), dim3(256), 0, stream,
                       cfb, coord, cell, phw, w1t, b1, w2t, b2, w3, b3, outp, b * kQ);
  }
}

// Round 4
// 1461.026 us; speedup vs baseline: 2.5822x; 1.5379x over previous
//
#include <hip/hip_runtime.h>
#include <math.h>

// ---------------- problem constants ----------------
namespace {
constexpr int kB   = 4;
constexpr int kNG  = 100;
constexpr int kH1  = 112;            // feat H/W
constexpr int kH2  = 224;            // upscaled H/W
constexpr int kQ   = kH2 * kH2;      // 50176 queries per batch image

// workspace layout (bytes). gf_hi/gf_lo overlap h (dead after k_wavg).
constexpr size_t OFF_H    = 0;                       // fp32 h [B][112][112][64] = 12,845,056
constexpr size_t OFF_GFH  = 0;                       // bf16 gfeat hi [224][224][64] = 6,422,528
constexpr size_t OFF_GFL  = 6422528;                 // bf16 gfeat lo
constexpr size_t OFF_CF   = 12845056;                // fp32 cf [224*224][512] = 102,760,448
constexpr size_t OFF_WPH  = OFF_CF + 102760448;      // conv2 W frag-order hi, 589,824
constexpr size_t OFF_WPL  = OFF_WPH + 589824;        // conv2 W frag-order lo
constexpr size_t OFF_WMLP = OFF_WPL + 589824;        // mlp W1/W2 frag-order hi/lo, 524,288
constexpr size_t OFF_WSUM = OFF_WMLP + 524288;
constexpr size_t OFF_WK   = OFF_WSUM + 1024;
// total ~117.35 MB (round-1's 129.3 MB fit, so this is safe)
}  // namespace

using s8v = __attribute__((ext_vector_type(8))) short;   // 8 bf16 (4 VGPRs)
using f4v = __attribute__((ext_vector_type(4))) float;   // MFMA acc

__device__ __forceinline__ unsigned short f2bf(float f) {
  unsigned int u = __float_as_uint(f);
  unsigned int r = u + 0x7fffu + ((u >> 16) & 1u);   // round-nearest-even
  return (unsigned short)(r >> 16);
}
__device__ __forceinline__ float bf2f(unsigned short h) {
  return __uint_as_float((unsigned int)h << 16);
}

// ---------------- tiny helpers ----------------
__global__ void k_init(float* wsums) {
  int t = threadIdx.x;
  if (t < 196) wsums[t] = 0.0f;
}

// Pack conv2 weights into MFMA B-fragment order, split bf16 hi/lo.
__global__ void k_prepw(const float* __restrict__ cw, const float* __restrict__ fw,
                        unsigned short* __restrict__ wph, unsigned short* __restrict__ wpl) {
  int e = blockIdx.x * 256 + threadIdx.x;   // 512*576 = 294912
  int co = e / 576, k = e % 576;
  int ci = k & 63, kk = k >> 6;
  float v = (co < 256) ? cw[co * 576 + ci * 9 + kk] : fw[(co - 256) * 576 + ci * 9 + kk];
  unsigned short hi = f2bf(v);
  unsigned short lo = f2bf(v - bf2f(hi));
  int n16 = co >> 4, nl = co & 15;
  int kstep = k >> 5, kr = k & 31;
  int dst = ((n16 * 18 + kstep) * 64 + (kr >> 3) * 16 + nl) * 8 + (kr & 7);
  wph[dst] = hi;
  wpl[dst] = lo;
}

// Pack MLP W1/W2 (out[j] = sum_k x[k]*W[j][k]) into B-frag order hi/lo.
// wmlp layout: [mat][plane hi/lo][65536 bf16]
__global__ void k_prepmlp(const float* __restrict__ w1, const float* __restrict__ w2,
                          unsigned short* __restrict__ wp) {
  int e = blockIdx.x * 256 + threadIdx.x;   // 131072
  int mat = e >> 16, idx = e & 65535;
  int j = idx >> 8, k = idx & 255;
  float v = (mat ? w2 : w1)[j * 256 + k];
  unsigned short hi = f2bf(v);
  unsigned short lo = f2bf(v - bf2f(hi));
  int n16 = j >> 4, nl = j & 15;
  int kstep = k >> 5, kr = k & 31;
  int dst = ((n16 * 8 + kstep) * 64 + (kr >> 3) * 16 + nl) * 8 + (kr & 7);
  wp[mat * 131072 + dst] = hi;
  wp[mat * 131072 + 65536 + dst] = lo;
}

// ---------------- 3x3 conv (pad=1), channel-major in, pixel-major out (conv1 only) ----------------
template <int IMG, int OSTRIDE, int NB, bool RELU>
__global__ __launch_bounds__(256) void k_conv3x3(
    const float* __restrict__ in, const float* __restrict__ wA, const float* __restrict__ bA,
    const float* __restrict__ wB, const float* __restrict__ bB, float* __restrict__ out) {
  constexpr int TILES = IMG / 8;
  constexpr int PER_COG = NB * TILES * TILES;
  const int t = threadIdx.x;
  int blk = blockIdx.x;
  const int cog = blk / PER_COG;
  int rem = blk % PER_COG;
  const int b = rem / (TILES * TILES);
  rem %= TILES * TILES;
  const int py0 = (rem / TILES) * 8;
  const int px0 = (rem % TILES) * 8;
  const int cobase = cog * 64;
  const float* wsrc = (cobase < 256) ? (wA + (size_t)cobase * 576)
                                     : (wB + (size_t)(cobase - 256) * 576);
  const float* bsrc = (cobase < 256) ? (bA + cobase) : (bB + (cobase - 256));

  __shared__ float in_s[16 * 10 * 12];
  __shared__ float wl_s[16 * 9 * 65];

  const int tc = t & 15;
  const int tp = t >> 4;
  const int rr = tp >> 1;
  const int cq = (tp & 1) * 4;

  float acc[4][4];
#pragma unroll
  for (int c = 0; c < 4; ++c)
#pragma unroll
    for (int j = 0; j < 4; ++j) acc[c][j] = 0.0f;

  for (int ck = 0; ck < 4; ++ck) {
    const int ci0 = ck * 16;
    for (int idx = t; idx < 1600; idx += 256) {
      int ci = idx / 100;
      int r2 = idx % 100;
      int iy = r2 / 10, ix = r2 % 10;
      int gy = py0 - 1 + iy, gx = px0 - 1 + ix;
      float v = 0.0f;
      if (gy >= 0 && gy < IMG && gx >= 0 && gx < IMG)
        v = in[(((size_t)b * 64 + ci0 + ci) * IMG + gy) * IMG + gx];
      in_s[(ci * 10 + iy) * 12 + ix] = v;
    }
    for (int idx = t; idx < 9216; idx += 256) {
      int col = idx / 144;
      int r2 = idx % 144;
      wl_s[r2 * 65 + col] = wsrc[((size_t)col * 64 + ci0) * 9 + r2];
    }
    __syncthreads();
#pragma unroll 2
    for (int ci = 0; ci < 16; ++ci) {
#pragma unroll
      for (int ky = 0; ky < 3; ++ky) {
#pragma unroll
        for (int kx = 0; kx < 3; ++kx) {
          const int kk = ky * 3 + kx;
          const float* wp = &wl_s[(ci * 9 + kk) * 65 + tc * 4];
          const float* ip = &in_s[(ci * 10 + rr + ky) * 12 + cq + kx];
          float wv[4], iv[4];
#pragma unroll
          for (int c = 0; c < 4; ++c) wv[c] = wp[c];
#pragma unroll
          for (int j = 0; j < 4; ++j) iv[j] = ip[j];
#pragma unroll
          for (int c = 0; c < 4; ++c)
#pragma unroll
            for (int j = 0; j < 4; ++j) acc[c][j] += wv[c] * iv[j];
        }
      }
    }
    __syncthreads();
  }
  float bias[4];
#pragma unroll
  for (int c = 0; c < 4; ++c) bias[c] = bsrc[tc * 4 + c];
#pragma unroll
  for (int j = 0; j < 4; ++j) {
    const int y = py0 + rr;
    const int x = px0 + cq + j;
    size_t pix = ((size_t)b * IMG + y) * IMG + x;
    float4 v;
    v.x = acc[0][j] + bias[0];
    v.y = acc[1][j] + bias[1];
    v.z = acc[2][j] + bias[2];
    v.w = acc[3][j] + bias[3];
    if (RELU) {
      v.x = fmaxf(v.x, 0.0f); v.y = fmaxf(v.y, 0.0f);
      v.z = fmaxf(v.z, 0.0f); v.w = fmaxf(v.w, 0.0f);
    }
    *(float4*)&out[pix * OSTRIDE + cobase + tc * 4] = v;
  }
}

// ---------------- 1x1 conv + softmax + weighted sums -> wsums[4][49] ----------------
__global__ __launch_bounds__(256) void k_wavg(
    const float* __restrict__ h, const float* __restrict__ w2, const float* __restrict__ b2,
    const float* __restrict__ sx, const float* __restrict__ sy,
    const float* __restrict__ op, const float* __restrict__ rho,
    float* __restrict__ wsums) {
  __shared__ float w2s[kNG * 64];
  __shared__ float prm[4 * kNG];
  __shared__ float b2s[kNG];
  __shared__ float pl[196];
  const int t = threadIdx.x;
  for (int i = t; i < kNG * 64; i += 256) w2s[i] = w2[i];
  if (t < kNG) {
    prm[t] = sx[t];
    prm[kNG + t] = sy[t];
    prm[2 * kNG + t] = op[t];
    prm[3 * kNG + t] = rho[t];
    b2s[t] = b2[t];
  }
  if (t < 196) pl[t] = 0.0f;
  __syncthreads();
  const int id = blockIdx.x * 256 + t;
  float hreg[64];
  const float4* hp = (const float4*)(h + (size_t)id * 64);
#pragma unroll
  for (int i = 0; i < 16; ++i) {
    float4 v = hp[i];
    hreg[4 * i] = v.x; hreg[4 * i + 1] = v.y;
    hreg[4 * i + 2] = v.z; hreg[4 * i + 3] = v.w;
  }
  float S = 0, Sx = 0, Sy = 0, So = 0, Sr = 0;
  for (int g = 0; g < kNG; ++g) {
    float d = b2s[g];
    const float4* wp = (const float4*)(w2s + g * 64);
#pragma unroll
    for (int i = 0; i < 16; ++i) {
      float4 w = wp[i];
      d += hreg[4 * i] * w.x + hreg[4 * i + 1] * w.y +
           hreg[4 * i + 2] * w.z + hreg[4 * i + 3] * w.w;
    }
    float e = expf(d);
    S += e;
    Sx += e * prm[g];
    Sy += e * prm[kNG + g];
    So += e * prm[2 * kNG + g];
    Sr += e * prm[3 * kNG + g];
  }
  const int rem = id % (kH1 * kH1);
  const int p = ((rem / kH1) % 7) * 7 + ((rem % kH1) % 7);
  const float inv = 1.0f / S;
  atomicAdd(&pl[p], Sx * inv);
  atomicAdd(&pl[49 + p], Sy * inv);
  atomicAdd(&pl[98 + p], So * inv);
  atomicAdd(&pl[147 + p], Sr * inv);
  __syncthreads();
  if (t < 196) atomicAdd(&wsums[t], pl[t]);
}

// ---------------- build wk[p][h][w] ----------------
__global__ __launch_bounds__(256) void k_finalize(const float* __restrict__ wsums,
                                                  float* __restrict__ wk) {
  __shared__ float kern_s[49 * 25];
  __shared__ float wavg_s[196];
  const int t = threadIdx.x;
  if (t < 196) wavg_s[t] = wsums[t] * (1.0f / 1024.0f);
  __syncthreads();
  if (t < 49) {
    float wsx = wavg_s[t], wsy = wavg_s[49 + t], wr = wavg_s[147 + t];
    float c00 = wsx * wsx + 1e-5f;
    float c11 = wsy * wsy + 1e-5f;
    float c01 = wr * wsx * wsy;
    float det = c00 * c11 - c01 * c01;
    float i00 = c11 / det, i11 = c00 / det, i01 = -c01 / det;
    float nrm = 1.0f / (2.0f * 3.14159265358979323846f * sqrtf(det));
    float vals[25];
    float mx = -1e30f;
#pragma unroll
    for (int i = 0; i < 5; ++i) {
#pragma unroll
      for (int j = 0; j < 5; ++j) {
        float yv = -5.0f + 2.5f * (float)i;
        float xv = -5.0f + 2.5f * (float)j;
        float z = -0.5f * (i00 * xv * xv + 2.0f * i01 * xv * yv + i11 * yv * yv);
        float v = expf(z) * nrm;
        vals[i * 5 + j] = v;
        mx = fmaxf(mx, v);
      }
    }
#pragma unroll
    for (int k = 0; k < 25; ++k) kern_s[t * 25 + k] = vals[k] / mx;
  }
  __syncthreads();
  for (int idx = t; idx < 49 * 196; idx += 256) {
    const int p = idx / 196;
    const int hw = idx % 196;
    const int hh = hw / 14, ww = hw % 14;
    float txv = (0.5f - (float)(p / 7) / 7.0f) * 2.0f;
    float tyv = (0.5f - (float)(p % 7) / 7.0f) * 2.0f;
    float gxv = (-1.0f + (float)ww * (2.0f / 13.0f)) + txv;
    float gyv = (-1.0f + (float)hh * (2.0f / 13.0f)) + tyv;
    float pxv = (gxv + 1.0f) * 0.5f * 13.0f;
    float pyv = (gyv + 1.0f) * 0.5f * 13.0f;
    float x0f = floorf(pxv), y0f = floorf(pyv);
    int x0 = (int)x0f, y0 = (int)y0f;
    float wx = pxv - x0f, wy = pyv - y0f;
    auto samp = [&](int yi, int xi) -> float {
      if (yi < 4 || yi >= 9 || xi < 4 || xi >= 9) return 0.0f;
      return kern_s[p * 25 + (yi - 4) * 5 + (xi - 4)];
    };
    float kt = samp(y0, x0) * (1.0f - wy) * (1.0f - wx) +
               samp(y0, x0 + 1) * (1.0f - wy) * wx +
               samp(y0 + 1, x0) * wy * (1.0f - wx) +
               samp(y0 + 1, x0 + 1) * wy * wx;
    wk[idx] = wavg_s[98 + p] * kt;
  }
}

// ---------------- splat (ONE image) -> pixel-major bf16 hi/lo gfeat ----------------
__global__ __launch_bounds__(256) void k_splat(const float* __restrict__ feat,
                                               const float* __restrict__ wk,
                                               unsigned short* __restrict__ gfh,
                                               unsigned short* __restrict__ gfl) {
  __shared__ float fs[64 * 49];
  __shared__ float wks[49 * 196];
  const int t = threadIdx.x;
  const int rem = blockIdx.x;   // 256 tiles
  const int ry = rem >> 4, rx = rem & 15;
  for (int idx = t; idx < 64 * 49; idx += 256) {
    int ci = idx / 49, p = idx % 49;
    int gy = ry * 7 + p / 7, gx = rx * 7 + p % 7;
    fs[idx] = feat[((size_t)ci * kH1 + gy) * kH1 + gx];
  }
  for (int idx = t; idx < 49 * 196; idx += 256) wks[idx] = wk[idx];
  __syncthreads();
  const int ci = t & 63;
  const int s = t >> 6;
  const int h0 = (s >> 1) * 7, w0 = (s & 1) * 7;
  float acc[49];
#pragma unroll
  for (int i = 0; i < 49; ++i) acc[i] = 0.0f;
  for (int p = 0; p < 49; ++p) {
    float f = fs[ci * 49 + p];
#pragma unroll
    for (int i = 0; i < 7; ++i)
#pragma unroll
      for (int j = 0; j < 7; ++j)
        acc[i * 7 + j] += f * wks[p * 196 + (h0 + i) * 14 + (w0 + j)];
  }
#pragma unroll
  for (int i = 0; i < 7; ++i)
#pragma unroll
    for (int j = 0; j < 7; ++j) {
      int Y = ry * 14 + h0 + i;
      int X = rx * 14 + w0 + j;
      float v = fminf(fmaxf(acc[i * 7 + j], 0.0f), 1.0f);
      unsigned short hi = f2bf(v);
      unsigned short lo = f2bf(v - bf2f(hi));
      size_t o = ((size_t)Y * kH2 + X) * 64 + ci;
      gfh[o] = hi;
      gfl[o] = lo;
    }
}

// ---------------- conv2 as bf16x3 MFMA implicit GEMM (ONE image) ----------------
__global__ __launch_bounds__(256, 2) void k_conv2_mfma(
    const unsigned short* __restrict__ gfh, const unsigned short* __restrict__ gfl,
    const unsigned short* __restrict__ wph, const unsigned short* __restrict__ wpl,
    const float* __restrict__ coef_b, const float* __restrict__ freq_b,
    float* __restrict__ outp) {
  __shared__ __attribute__((aligned(16))) char Asb[2 * 180 * 144];
  const int t = threadIdx.x;
  const int blk = blockIdx.x;       // 392 Mtiles * 2 Nhalves
  const int nb = blk & 1;
  const int mt = blk >> 1;
  const int ty = mt / 28, tx = mt % 28;
  const int py0 = ty * 16, px0 = tx * 8;

  for (int idx = t; idx < 2880; idx += 256) {
    int plane = idx >= 1440;
    int r2 = plane ? idx - 1440 : idx;
    int p = r2 >> 3, c8 = r2 & 7;
    int pr = p / 10, pc = p % 10;
    int gy = py0 - 1 + pr, gx = px0 - 1 + pc;
    uint4 u = make_uint4(0u, 0u, 0u, 0u);
    if (gy >= 0 && gy < kH2 && gx >= 0 && gx < kH2) {
      const unsigned short* src = (plane ? gfl : gfh) + ((size_t)(gy * kH2 + gx)) * 64 + c8 * 8;
      u = *(const uint4*)src;
    }
    *(uint4*)(Asb + plane * 25920 + p * 144 + c8 * 16) = u;
  }
  __syncthreads();

  const int w = t >> 6, lane = t & 63;
  const int quad = lane >> 4, ml = lane & 15;
  const int abase = (((ml >> 3) * 10) + (ml & 7)) * 144 + quad * 16;
  const int n16base = nb * 16 + w * 4;
  const unsigned int bvoff = (unsigned int)lane * 16u;

  f4v acc[8][4];
#pragma unroll
  for (int i = 0; i < 8; ++i)
#pragma unroll
    for (int j = 0; j < 4; ++j) acc[i][j] = (f4v){0.0f, 0.0f, 0.0f, 0.0f};

#pragma unroll
  for (int kk = 0; kk < 9; ++kk) {
    const int ky = kk / 3, kx = kk % 3;
#pragma unroll
    for (int cs = 0; cs < 2; ++cs) {
      const int kstep = kk * 2 + cs;
      s8v Bh[4], Bl[4];
#pragma unroll
      for (int j = 0; j < 4; ++j) {
        unsigned int off = ((unsigned int)(n16base + j) * 18u + (unsigned int)kstep) * 1024u + bvoff;
        Bh[j] = *(const s8v*)((const char*)wph + off);
        Bl[j] = *(const s8v*)((const char*)wpl + off);
      }
#pragma unroll
      for (int i = 0; i < 8; ++i) {
        const int aoff = ((2 * i + ky) * 10 + kx) * 144 + cs * 64 + abase;
        s8v Ah = *(const s8v*)(Asb + aoff);
        s8v Al = *(const s8v*)(Asb + 25920 + aoff);
#pragma unroll
        for (int j = 0; j < 4; ++j) {
          acc[i][j] = __builtin_amdgcn_mfma_f32_16x16x32_bf16(Ah, Bh[j], acc[i][j], 0, 0, 0);
          acc[i][j] = __builtin_amdgcn_mfma_f32_16x16x32_bf16(Al, Bh[j], acc[i][j], 0, 0, 0);
          acc[i][j] = __builtin_amdgcn_mfma_f32_16x16x32_bf16(Ah, Bl[j], acc[i][j], 0, 0, 0);
        }
      }
    }
  }

  const int cobase = nb * 256 + w * 64;
  float bj[4];
#pragma unroll
  for (int j = 0; j < 4; ++j) {
    int co = cobase + j * 16 + ml;
    bj[j] = (co < 256) ? coef_b[co] : freq_b[co - 256];
  }
#pragma unroll
  for (int i = 0; i < 8; ++i) {
#pragma unroll
    for (int reg = 0; reg < 4; ++reg) {
      int m = i * 16 + quad * 4 + reg;
      int Y = py0 + (m >> 3), X = px0 + (m & 7);
      float* o = outp + ((size_t)(Y * kH2 + X)) * 512 + cobase + ml;
#pragma unroll
      for (int j = 0; j < 4; ++j) o[j * 16] = acc[i][j][reg] + bj[j];
    }
  }
}

// ---------------- fused query (ONE image): gather + basis + bf16x3 MFMA MLP ----------------
// Block: 64 queries, 4 waves; wave = M64 x N64 per layer; W frag-direct from L2.
__global__ __launch_bounds__(256, 2) void k_query_mfma(
    const float* __restrict__ cf, const float* __restrict__ coord,
    const float* __restrict__ cell, const float* __restrict__ phw,
    const unsigned short* __restrict__ wmlp,   // [2][hi/lo][65536]
    const float* __restrict__ b1, const float* __restrict__ b2,
    const float* __restrict__ w3, const float* __restrict__ b3,
    float* __restrict__ out, int q_base) {
  // X as bf16 hi/lo planes, rows m=query (64), 264-elem padded rows.
  // Union'd as fp32 [64][264] after layer 2.
  __shared__ __attribute__((aligned(16))) char Xs[2 * 64 * 264 * 2];  // 67,584 B
  constexpr int ROW = 264 * 2;         // bf16 row bytes
  constexpr int PLANE = 64 * 264 * 2;  // 33,792
  const int t = threadIdx.x;
  const int q0 = q_base + blockIdx.x * 64;

  // ---- phase 1: gather + basis -> bf16 hi/lo A-layout in LDS ----
  {
    const int tq = t >> 2, ts = t & 3;
    const int qg = q0 + tq;
    float gy = coord[(size_t)qg * 2 + 0];
    float gx = coord[(size_t)qg * 2 + 1];
    float fx = ((gx + 1.0f) * 224.0f - 1.0f) * 0.5f;
    float fy = ((gy + 1.0f) * 224.0f - 1.0f) * 0.5f;
    int ix = (int)rintf(fx);
    int iy = (int)rintf(fy);
    bool ok = (ix >= 0) && (ix < 224) && (iy >= 0) && (iy < 224);
    int ixc = min(max(ix, 0), 223);
    int iyc = min(max(iy, 0), 223);
    float m = ok ? 1.0f : 0.0f;
    float qcy = ok ? (-1.0f + (1.0f / 224.0f) + (2.0f / 224.0f) * (float)iyc) : 0.0f;
    float qcx = ok ? (-1.0f + (1.0f / 224.0f) + (2.0f / 224.0f) * (float)ixc) : 0.0f;
    float rel0 = (gy - qcy) * 224.0f;
    float rel1 = (gx - qcx) * 224.0f;
    float rc0 = cell[(size_t)qg * 2 + 0] * 224.0f;
    float rc1 = cell[(size_t)qg * 2 + 1] * 224.0f;
    const float* base = cf + (((size_t)iyc * kH2 + ixc) * 512);
    unsigned short ch_[8], cl_[8], sh_[8], sl_[8];
#pragma unroll
    for (int u = 0; u < 8; ++u) {
      const int k4 = ts * 32 + u * 4;
      float4 clo = *(const float4*)(base + k4);
      float4 chi = *(const float4*)(base + 128 + k4);
      float4 f0 = *(const float4*)(base + 256 + 2 * k4);
      float4 f1 = *(const float4*)(base + 256 + 2 * k4 + 4);
      float fr[8] = {f0.x, f0.y, f0.z, f0.w, f1.x, f1.y, f1.z, f1.w};
      float cl4[4] = {clo.x, clo.y, clo.z, clo.w};
      float ch4[4] = {chi.x, chi.y, chi.z, chi.w};
#pragma unroll
      for (int e = 0; e < 4; ++e) {
        const int k = k4 + e;
        float ph = rc0 * phw[2 * k] + rc1 * phw[2 * k + 1];
        float s = m * (fr[2 * e] * rel0 + fr[2 * e + 1] * rel1) + ph;
        float sv, cv;
        sincospif(s, &sv, &cv);
        float xc = m * cl4[e] * cv;
        float xsn = m * ch4[e] * sv;
        const int sl = (u & 1) * 4 + e;
        unsigned short h1_ = f2bf(xc);
        ch_[sl] = h1_; cl_[sl] = f2bf(xc - bf2f(h1_));
        unsigned short h2_ = f2bf(xsn);
        sh_[sl] = h2_; sl_[sl] = f2bf(xsn - bf2f(h2_));
      }
      if (u & 1) {
        const int kb = ts * 32 + (u - 1) * 4;
        uint4 v;
        v.x = (unsigned)ch_[0] | ((unsigned)ch_[1] << 16);
        v.y = (unsigned)ch_[2] | ((unsigned)ch_[3] << 16);
        v.z = (unsigned)ch_[4] | ((unsigned)ch_[5] << 16);
        v.w = (unsigned)ch_[6] | ((unsigned)ch_[7] << 16);
        *(uint4*)(Xs + tq * ROW + kb * 2) = v;
        v.x = (unsigned)cl_[0] | ((unsigned)cl_[1] << 16);
        v.y = (unsigned)cl_[2] | ((unsigned)cl_[3] << 16);
        v.z = (unsigned)cl_[4] | ((unsigned)cl_[5] << 16);
        v.w = (unsigned)cl_[6] | ((unsigned)cl_[7] << 16);
        *(uint4*)(Xs + PLANE + tq * ROW + kb * 2) = v;
        v.x = (unsigned)sh_[0] | ((unsigned)sh_[1] << 16);
        v.y = (unsigned)sh_[2] | ((unsigned)sh_[3] << 16);
        v.z = (unsigned)sh_[4] | ((unsigned)sh_[5] << 16);
        v.w = (unsigned)sh_[6] | ((unsigned)sh_[7] << 16);
        *(uint4*)(Xs + tq * ROW + (128 + kb) * 2) = v;
        v.x = (unsigned)sl_[0] | ((unsigned)sl_[1] << 16);
        v.y = (unsigned)sl_[2] | ((unsigned)sl_[3] << 16);
        v.z = (unsigned)sl_[4] | ((unsigned)sl_[5] << 16);
        v.w = (unsigned)sl_[6] | ((unsigned)sl_[7] << 16);
        *(uint4*)(Xs + PLANE + tq * ROW + (128 + kb) * 2) = v;
      }
    }
  }
  __syncthreads();

  const int w = t >> 6, lane = t & 63;
  const int quad = lane >> 4, ml = lane & 15;
  const unsigned int bvoff = (unsigned int)lane * 16u;

#pragma unroll
  for (int layer = 0; layer < 2; ++layer) {
    const unsigned short* wb = wmlp + layer * 131072;
    f4v acc[4][4];
#pragma unroll
    for (int i = 0; i < 4; ++i)
#pragma unroll
      for (int j = 0; j < 4; ++j) acc[i][j] = (f4v){0.0f, 0.0f, 0.0f, 0.0f};
#pragma unroll
    for (int kstep = 0; kstep < 8; ++kstep) {
      s8v Bh[4], Bl[4];
#pragma unroll
      for (int j = 0; j < 4; ++j) {
        unsigned int off = (unsigned int)((w * 4 + j) * 8 + kstep) * 1024u + bvoff;
        Bh[j] = *(const s8v*)((const char*)wb + off);
        Bl[j] = *(const s8v*)((const char*)(wb + 65536) + off);
      }
#pragma unroll
      for (int i = 0; i < 4; ++i) {
        const int aoff = (i * 16 + ml) * ROW + (kstep * 32 + quad * 8) * 2;
        s8v Ah = *(const s8v*)(Xs + aoff);
        s8v Al = *(const s8v*)(Xs + PLANE + aoff);
#pragma unroll
        for (int j = 0; j < 4; ++j) {
          acc[i][j] = __builtin_amdgcn_mfma_f32_16x16x32_bf16(Ah, Bh[j], acc[i][j], 0, 0, 0);
          acc[i][j] = __builtin_amdgcn_mfma_f32_16x16x32_bf16(Al, Bh[j], acc[i][j], 0, 0, 0);
          acc[i][j] = __builtin_amdgcn_mfma_f32_16x16x32_bf16(Ah, Bl[j], acc[i][j], 0, 0, 0);
        }
      }
    }
    __syncthreads();   // all reads of Xs complete before overwrite
    const float* bs = layer ? b2 : b1;
    float bj[4];
#pragma unroll
    for (int j = 0; j < 4; ++j) bj[j] = bs[w * 64 + j * 16 + ml];
    if (layer == 0) {
#pragma unroll
      for (int i = 0; i < 4; ++i)
#pragma unroll
        for (int j = 0; j < 4; ++j)
#pragma unroll
          for (int reg = 0; reg < 4; ++reg) {
            int m = i * 16 + quad * 4 + reg;
            int n = w * 64 + j * 16 + ml;
            float v = fmaxf(acc[i][j][reg] + bj[j], 0.0f);
            unsigned short hi = f2bf(v);
            unsigned short lo = f2bf(v - bf2f(hi));
            *(unsigned short*)(Xs + m * ROW + n * 2) = hi;
            *(unsigned short*)(Xs + PLANE + m * ROW + n * 2) = lo;
          }
    } else {
      // fp32 X rows [64][264] (exactly fills the 67,584 B union)
#pragma unroll
      for (int i = 0; i < 4; ++i)
#pragma unroll
        for (int j = 0; j < 4; ++j)
#pragma unroll
          for (int reg = 0; reg < 4; ++reg) {
            int m = i * 16 + quad * 4 + reg;
            int n = w * 64 + j * 16 + ml;
            float v = fmaxf(acc[i][j][reg] + bj[j], 0.0f);
            *(float*)(Xs + ((size_t)m * 264 + n) * 4) = v;
          }
    }
    __syncthreads();
  }

  // ---- phase 3: 3-wide output layer ----
  {
    const int tq = t >> 2, ts = t & 3;
    const float* xr = (const float*)(Xs + (size_t)tq * 264 * 4);
    float c0 = 0, c1 = 0, c2 = 0;
    for (int k = ts * 64; k < ts * 64 + 64; ++k) {
      float xv = xr[k];
      c0 += xv * w3[k];
      c1 += xv * w3[256 + k];
      c2 += xv * w3[512 + k];
    }
    c0 += __shfl_down(c0, 2, 4); c0 += __shfl_down(c0, 1, 4);
    c1 += __shfl_down(c1, 2, 4); c1 += __shfl_down(c1, 1, 4);
    c2 += __shfl_down(c2, 2, 4); c2 += __shfl_down(c2, 1, 4);
    if (ts == 0) {
      const int qg = q0 + tq;
      float* o = out + (size_t)qg * 3;
      o[0] = c0 + b3[0];
      o[1] = c1 + b3[1];
      o[2] = c2 + b3[2];
    }
  }
}

// ---------------- launch ----------------
extern "C" void kernel_launch(void* const* d_in, const int* in_sizes, int n_in,
                              void* d_out, int out_size, void* d_ws, size_t ws_size,
                              hipStream_t stream) {
  (void)in_sizes; (void)n_in; (void)out_size; (void)ws_size;
  const float* feat   = (const float*)d_in[0];
  const float* coord  = (const float*)d_in[1];
  const float* cell   = (const float*)d_in[2];
  const float* cls_w1 = (const float*)d_in[3];
  const float* cls_b1 = (const float*)d_in[4];
  const float* cls_w2 = (const float*)d_in[5];
  const float* cls_b2 = (const float*)d_in[6];
  const float* sigx   = (const float*)d_in[7];
  const float* sigy   = (const float*)d_in[8];
  const float* opac   = (const float*)d_in[9];
  const float* rho    = (const float*)d_in[10];
  const float* coef_w = (const float*)d_in[11];
  const float* coef_b = (const float*)d_in[12];
  const float* freq_w = (const float*)d_in[13];
  const float* freq_b = (const float*)d_in[14];
  const float* phw    = (const float*)d_in[15];
  const float* w1     = (const float*)d_in[16];
  const float* b1     = (const float*)d_in[17];
  const float* w2     = (const float*)d_in[18];
  const float* b2     = (const float*)d_in[19];
  const float* w3     = (const float*)d_in[20];
  const float* b3     = (const float*)d_in[21];

  char* ws = (char*)d_ws;
  float* h_buf = (float*)(ws + OFF_H);
  unsigned short* gfh = (unsigned short*)(ws + OFF_GFH);
  unsigned short* gfl = (unsigned short*)(ws + OFF_GFL);
  float* cfb   = (float*)(ws + OFF_CF);
  unsigned short* wph = (unsigned short*)(ws + OFF_WPH);
  unsigned short* wpl = (unsigned short*)(ws + OFF_WPL);
  unsigned short* wmlp = (unsigned short*)(ws + OFF_WMLP);
  float* wsums = (float*)(ws + OFF_WSUM);
  float* wk    = (float*)(ws + OFF_WK);
  float* outp  = (float*)d_out;

  hipLaunchKernelGGL(k_init, dim3(1), dim3(256), 0, stream, wsums);
  hipLaunchKernelGGL(k_prepw, dim3(1152), dim3(256), 0, stream, coef_w, freq_w, wph, wpl);
  hipLaunchKernelGGL(k_prepmlp, dim3(512), dim3(256), 0, stream, w1, w2, wmlp);
  hipLaunchKernelGGL((k_conv3x3<112, 64, 4, true>), dim3(784), dim3(256), 0, stream,
                     feat, cls_w1, cls_b1, cls_w1, cls_b1, h_buf);
  hipLaunchKernelGGL(k_wavg, dim3(196), dim3(256), 0, stream,
                     h_buf, cls_w2, cls_b2, sigx, sigy, opac, rho, wsums);
  hipLaunchKernelGGL(k_finalize, dim3(1), dim3(256), 0, stream, wsums, wk);

  for (int b = 0; b < kB; ++b) {
    const float* feat_b = feat + (size_t)b * 64 * kH1 * kH1;
    hipLaunchKernelGGL(k_splat, dim3(256), dim3(256), 0, stream, feat_b, wk, gfh, gfl);
    hipLaunchKernelGGL(k_conv2_mfma, dim3(784), dim3(256), 0, stream,
                       gfh, gfl, wph, wpl, coef_b, freq_b, cfb);
    hipLaunchKernelGGL(k_query_mfma, dim3(784), dim3(256), 0, stream,
                       cfb, coord, cell, phw, wmlp, b1, b2, w3, b3, outp, b * kQ);
  }
}

// Round 5
// 1386.732 us; speedup vs baseline: 2.7206x; 1.0536x over previous
//
#include <hip/hip_runtime.h>
#include <math.h>

// ---------------- problem constants ----------------
namespace {
constexpr int kB   = 4;
constexpr int kNG  = 100;
constexpr int kH1  = 112;            // feat H/W
constexpr int kH2  = 224;            // upscaled H/W
constexpr int kQ   = kH2 * kH2;      // 50176 queries per batch image

// workspace layout (bytes). gf_hi/gf_lo overlap h (dead after k_wavg).
constexpr size_t OFF_H    = 0;                       // fp32 h [B][112][112][64] = 12,845,056
constexpr size_t OFF_GFH  = 0;                       // bf16 gfeat hi [224][224][64] = 6,422,528
constexpr size_t OFF_GFL  = 6422528;                 // bf16 gfeat lo
constexpr size_t OFF_CF   = 12845056;                // fp32 cf [224*224][512] = 102,760,448
constexpr size_t OFF_WPH  = OFF_CF + 102760448;      // conv2 W frag-order hi, 589,824
constexpr size_t OFF_WPL  = OFF_WPH + 589824;        // conv2 W frag-order lo
constexpr size_t OFF_WMLP = OFF_WPL + 589824;        // mlp W1/W2 frag-order hi/lo, 524,288
constexpr size_t OFF_WSUM = OFF_WMLP + 524288;
constexpr size_t OFF_WK   = OFF_WSUM + 1024;
// total ~117.35 MB
}  // namespace

using s8v = __attribute__((ext_vector_type(8))) short;   // 8 bf16 (4 VGPRs)
using f4v = __attribute__((ext_vector_type(4))) float;   // MFMA acc

__device__ __forceinline__ unsigned short f2bf(float f) {
  unsigned int u = __float_as_uint(f);
  unsigned int r = u + 0x7fffu + ((u >> 16) & 1u);   // round-nearest-even
  return (unsigned short)(r >> 16);
}
__device__ __forceinline__ float bf2f(unsigned short h) {
  return __uint_as_float((unsigned int)h << 16);
}

// ---------------- tiny helpers ----------------
__global__ void k_init(float* wsums) {
  int t = threadIdx.x;
  if (t < 196) wsums[t] = 0.0f;
}

// Pack conv2 weights into MFMA B-fragment order, split bf16 hi/lo.
__global__ void k_prepw(const float* __restrict__ cw, const float* __restrict__ fw,
                        unsigned short* __restrict__ wph, unsigned short* __restrict__ wpl) {
  int e = blockIdx.x * 256 + threadIdx.x;   // 512*576 = 294912
  int co = e / 576, k = e % 576;
  int ci = k & 63, kk = k >> 6;
  float v = (co < 256) ? cw[co * 576 + ci * 9 + kk] : fw[(co - 256) * 576 + ci * 9 + kk];
  unsigned short hi = f2bf(v);
  unsigned short lo = f2bf(v - bf2f(hi));
  int n16 = co >> 4, nl = co & 15;
  int kstep = k >> 5, kr = k & 31;
  int dst = ((n16 * 18 + kstep) * 64 + (kr >> 3) * 16 + nl) * 8 + (kr & 7);
  wph[dst] = hi;
  wpl[dst] = lo;
}

// Pack MLP W1/W2 into B-frag order hi/lo. wmlp layout: [mat][hi/lo][65536 bf16]
__global__ void k_prepmlp(const float* __restrict__ w1, const float* __restrict__ w2,
                          unsigned short* __restrict__ wp) {
  int e = blockIdx.x * 256 + threadIdx.x;   // 131072
  int mat = e >> 16, idx = e & 65535;
  int j = idx >> 8, k = idx & 255;
  float v = (mat ? w2 : w1)[j * 256 + k];
  unsigned short hi = f2bf(v);
  unsigned short lo = f2bf(v - bf2f(hi));
  int n16 = j >> 4, nl = j & 15;
  int kstep = k >> 5, kr = k & 31;
  int dst = ((n16 * 8 + kstep) * 64 + (kr >> 3) * 16 + nl) * 8 + (kr & 7);
  wp[mat * 131072 + dst] = hi;
  wp[mat * 131072 + 65536 + dst] = lo;
}

// ---------------- 3x3 conv (pad=1), channel-major in, pixel-major out (conv1 only) ----------------
template <int IMG, int OSTRIDE, int NB, bool RELU>
__global__ __launch_bounds__(256) void k_conv3x3(
    const float* __restrict__ in, const float* __restrict__ wA, const float* __restrict__ bA,
    const float* __restrict__ wB, const float* __restrict__ bB, float* __restrict__ out) {
  constexpr int TILES = IMG / 8;
  constexpr int PER_COG = NB * TILES * TILES;
  const int t = threadIdx.x;
  int blk = blockIdx.x;
  const int cog = blk / PER_COG;
  int rem = blk % PER_COG;
  const int b = rem / (TILES * TILES);
  rem %= TILES * TILES;
  const int py0 = (rem / TILES) * 8;
  const int px0 = (rem % TILES) * 8;
  const int cobase = cog * 64;
  const float* wsrc = (cobase < 256) ? (wA + (size_t)cobase * 576)
                                     : (wB + (size_t)(cobase - 256) * 576);
  const float* bsrc = (cobase < 256) ? (bA + cobase) : (bB + (cobase - 256));

  __shared__ float in_s[16 * 10 * 12];
  __shared__ float wl_s[16 * 9 * 65];

  const int tc = t & 15;
  const int tp = t >> 4;
  const int rr = tp >> 1;
  const int cq = (tp & 1) * 4;

  float acc[4][4];
#pragma unroll
  for (int c = 0; c < 4; ++c)
#pragma unroll
    for (int j = 0; j < 4; ++j) acc[c][j] = 0.0f;

  for (int ck = 0; ck < 4; ++ck) {
    const int ci0 = ck * 16;
    for (int idx = t; idx < 1600; idx += 256) {
      int ci = idx / 100;
      int r2 = idx % 100;
      int iy = r2 / 10, ix = r2 % 10;
      int gy = py0 - 1 + iy, gx = px0 - 1 + ix;
      float v = 0.0f;
      if (gy >= 0 && gy < IMG && gx >= 0 && gx < IMG)
        v = in[(((size_t)b * 64 + ci0 + ci) * IMG + gy) * IMG + gx];
      in_s[(ci * 10 + iy) * 12 + ix] = v;
    }
    for (int idx = t; idx < 9216; idx += 256) {
      int col = idx / 144;
      int r2 = idx % 144;
      wl_s[r2 * 65 + col] = wsrc[((size_t)col * 64 + ci0) * 9 + r2];
    }
    __syncthreads();
#pragma unroll 2
    for (int ci = 0; ci < 16; ++ci) {
#pragma unroll
      for (int ky = 0; ky < 3; ++ky) {
#pragma unroll
        for (int kx = 0; kx < 3; ++kx) {
          const int kk = ky * 3 + kx;
          const float* wp = &wl_s[(ci * 9 + kk) * 65 + tc * 4];
          const float* ip = &in_s[(ci * 10 + rr + ky) * 12 + cq + kx];
          float wv[4], iv[4];
#pragma unroll
          for (int c = 0; c < 4; ++c) wv[c] = wp[c];
#pragma unroll
          for (int j = 0; j < 4; ++j) iv[j] = ip[j];
#pragma unroll
          for (int c = 0; c < 4; ++c)
#pragma unroll
            for (int j = 0; j < 4; ++j) acc[c][j] += wv[c] * iv[j];
        }
      }
    }
    __syncthreads();
  }
  float bias[4];
#pragma unroll
  for (int c = 0; c < 4; ++c) bias[c] = bsrc[tc * 4 + c];
#pragma unroll
  for (int j = 0; j < 4; ++j) {
    const int y = py0 + rr;
    const int x = px0 + cq + j;
    size_t pix = ((size_t)b * IMG + y) * IMG + x;
    float4 v;
    v.x = acc[0][j] + bias[0];
    v.y = acc[1][j] + bias[1];
    v.z = acc[2][j] + bias[2];
    v.w = acc[3][j] + bias[3];
    if (RELU) {
      v.x = fmaxf(v.x, 0.0f); v.y = fmaxf(v.y, 0.0f);
      v.z = fmaxf(v.z, 0.0f); v.w = fmaxf(v.w, 0.0f);
    }
    *(float4*)&out[pix * OSTRIDE + cobase + tc * 4] = v;
  }
}

// ---------------- 1x1 conv + softmax + weighted sums -> wsums[4][49] ----------------
__global__ __launch_bounds__(256) void k_wavg(
    const float* __restrict__ h, const float* __restrict__ w2, const float* __restrict__ b2,
    const float* __restrict__ sx, const float* __restrict__ sy,
    const float* __restrict__ op, const float* __restrict__ rho,
    float* __restrict__ wsums) {
  __shared__ float w2s[kNG * 64];
  __shared__ float prm[4 * kNG];
  __shared__ float b2s[kNG];
  __shared__ float pl[196];
  const int t = threadIdx.x;
  for (int i = t; i < kNG * 64; i += 256) w2s[i] = w2[i];
  if (t < kNG) {
    prm[t] = sx[t];
    prm[kNG + t] = sy[t];
    prm[2 * kNG + t] = op[t];
    prm[3 * kNG + t] = rho[t];
    b2s[t] = b2[t];
  }
  if (t < 196) pl[t] = 0.0f;
  __syncthreads();
  const int id = blockIdx.x * 256 + t;
  float hreg[64];
  const float4* hp = (const float4*)(h + (size_t)id * 64);
#pragma unroll
  for (int i = 0; i < 16; ++i) {
    float4 v = hp[i];
    hreg[4 * i] = v.x; hreg[4 * i + 1] = v.y;
    hreg[4 * i + 2] = v.z; hreg[4 * i + 3] = v.w;
  }
  float S = 0, Sx = 0, Sy = 0, So = 0, Sr = 0;
  for (int g = 0; g < kNG; ++g) {
    float d = b2s[g];
    const float4* wp = (const float4*)(w2s + g * 64);
#pragma unroll
    for (int i = 0; i < 16; ++i) {
      float4 w = wp[i];
      d += hreg[4 * i] * w.x + hreg[4 * i + 1] * w.y +
           hreg[4 * i + 2] * w.z + hreg[4 * i + 3] * w.w;
    }
    float e = expf(d);
    S += e;
    Sx += e * prm[g];
    Sy += e * prm[kNG + g];
    So += e * prm[2 * kNG + g];
    Sr += e * prm[3 * kNG + g];
  }
  const int rem = id % (kH1 * kH1);
  const int p = ((rem / kH1) % 7) * 7 + ((rem % kH1) % 7);
  const float inv = 1.0f / S;
  atomicAdd(&pl[p], Sx * inv);
  atomicAdd(&pl[49 + p], Sy * inv);
  atomicAdd(&pl[98 + p], So * inv);
  atomicAdd(&pl[147 + p], Sr * inv);
  __syncthreads();
  if (t < 196) atomicAdd(&wsums[t], pl[t]);
}

// ---------------- build wk[p][h][w] ----------------
__global__ __launch_bounds__(256) void k_finalize(const float* __restrict__ wsums,
                                                  float* __restrict__ wk) {
  __shared__ float kern_s[49 * 25];
  __shared__ float wavg_s[196];
  const int t = threadIdx.x;
  if (t < 196) wavg_s[t] = wsums[t] * (1.0f / 1024.0f);
  __syncthreads();
  if (t < 49) {
    float wsx = wavg_s[t], wsy = wavg_s[49 + t], wr = wavg_s[147 + t];
    float c00 = wsx * wsx + 1e-5f;
    float c11 = wsy * wsy + 1e-5f;
    float c01 = wr * wsx * wsy;
    float det = c00 * c11 - c01 * c01;
    float i00 = c11 / det, i11 = c00 / det, i01 = -c01 / det;
    float nrm = 1.0f / (2.0f * 3.14159265358979323846f * sqrtf(det));
    float vals[25];
    float mx = -1e30f;
#pragma unroll
    for (int i = 0; i < 5; ++i) {
#pragma unroll
      for (int j = 0; j < 5; ++j) {
        float yv = -5.0f + 2.5f * (float)i;
        float xv = -5.0f + 2.5f * (float)j;
        float z = -0.5f * (i00 * xv * xv + 2.0f * i01 * xv * yv + i11 * yv * yv);
        float v = expf(z) * nrm;
        vals[i * 5 + j] = v;
        mx = fmaxf(mx, v);
      }
    }
#pragma unroll
    for (int k = 0; k < 25; ++k) kern_s[t * 25 + k] = vals[k] / mx;
  }
  __syncthreads();
  for (int idx = t; idx < 49 * 196; idx += 256) {
    const int p = idx / 196;
    const int hw = idx % 196;
    const int hh = hw / 14, ww = hw % 14;
    float txv = (0.5f - (float)(p / 7) / 7.0f) * 2.0f;
    float tyv = (0.5f - (float)(p % 7) / 7.0f) * 2.0f;
    float gxv = (-1.0f + (float)ww * (2.0f / 13.0f)) + txv;
    float gyv = (-1.0f + (float)hh * (2.0f / 13.0f)) + tyv;
    float pxv = (gxv + 1.0f) * 0.5f * 13.0f;
    float pyv = (gyv + 1.0f) * 0.5f * 13.0f;
    float x0f = floorf(pxv), y0f = floorf(pyv);
    int x0 = (int)x0f, y0 = (int)y0f;
    float wx = pxv - x0f, wy = pyv - y0f;
    auto samp = [&](int yi, int xi) -> float {
      if (yi < 4 || yi >= 9 || xi < 4 || xi >= 9) return 0.0f;
      return kern_s[p * 25 + (yi - 4) * 5 + (xi - 4)];
    };
    float kt = samp(y0, x0) * (1.0f - wy) * (1.0f - wx) +
               samp(y0, x0 + 1) * (1.0f - wy) * wx +
               samp(y0 + 1, x0) * wy * (1.0f - wx) +
               samp(y0 + 1, x0 + 1) * wy * wx;
    wk[idx] = wavg_s[98 + p] * kt;
  }
}

// ---------------- splat (ONE image) -> pixel-major bf16 hi/lo gfeat ----------------
__global__ __launch_bounds__(256) void k_splat(const float* __restrict__ feat,
                                               const float* __restrict__ wk,
                                               unsigned short* __restrict__ gfh,
                                               unsigned short* __restrict__ gfl) {
  __shared__ float fs[64 * 49];
  __shared__ float wks[49 * 196];
  const int t = threadIdx.x;
  const int rem = blockIdx.x;   // 256 tiles
  const int ry = rem >> 4, rx = rem & 15;
  for (int idx = t; idx < 64 * 49; idx += 256) {
    int ci = idx / 49, p = idx % 49;
    int gy = ry * 7 + p / 7, gx = rx * 7 + p % 7;
    fs[idx] = feat[((size_t)ci * kH1 + gy) * kH1 + gx];
  }
  for (int idx = t; idx < 49 * 196; idx += 256) wks[idx] = wk[idx];
  __syncthreads();
  const int ci = t & 63;
  const int s = t >> 6;
  const int h0 = (s >> 1) * 7, w0 = (s & 1) * 7;
  float acc[49];
#pragma unroll
  for (int i = 0; i < 49; ++i) acc[i] = 0.0f;
  for (int p = 0; p < 49; ++p) {
    float f = fs[ci * 49 + p];
#pragma unroll
    for (int i = 0; i < 7; ++i)
#pragma unroll
      for (int j = 0; j < 7; ++j)
        acc[i * 7 + j] += f * wks[p * 196 + (h0 + i) * 14 + (w0 + j)];
  }
#pragma unroll
  for (int i = 0; i < 7; ++i)
#pragma unroll
    for (int j = 0; j < 7; ++j) {
      int Y = ry * 14 + h0 + i;
      int X = rx * 14 + w0 + j;
      float v = fminf(fmaxf(acc[i * 7 + j], 0.0f), 1.0f);
      unsigned short hi = f2bf(v);
      unsigned short lo = f2bf(v - bf2f(hi));
      size_t o = ((size_t)Y * kH2 + X) * 64 + ci;
      gfh[o] = hi;
      gfl[o] = lo;
    }
}

// ---------------- conv2 as bf16x3 MFMA implicit GEMM (ONE image) ----------------
// Epilogue routes through LDS so global stores are full 128-B lines
// (round-4 counters: scalar scattered stores caused 3.8x write amplification
//  + write-allocate fetch -> kernel was HBM-bound at 2.9 TB/s).
__global__ __launch_bounds__(256, 2) void k_conv2_mfma(
    const unsigned short* __restrict__ gfh, const unsigned short* __restrict__ gfl,
    const unsigned short* __restrict__ wph, const unsigned short* __restrict__ wpl,
    const float* __restrict__ coef_b, const float* __restrict__ freq_b,
    float* __restrict__ outp) {
  __shared__ __attribute__((aligned(16))) char Asb[2 * 180 * 144];  // 51,840 B
  const int t = threadIdx.x;
  const int blk = blockIdx.x;       // 392 Mtiles * 2 Nhalves
  const int nb = blk & 1;
  const int mt = blk >> 1;
  const int ty = mt / 28, tx = mt % 28;
  const int py0 = ty * 16, px0 = tx * 8;

  for (int idx = t; idx < 2880; idx += 256) {
    int plane = idx >= 1440;
    int r2 = plane ? idx - 1440 : idx;
    int p = r2 >> 3, c8 = r2 & 7;
    int pr = p / 10, pc = p % 10;
    int gy = py0 - 1 + pr, gx = px0 - 1 + pc;
    uint4 u = make_uint4(0u, 0u, 0u, 0u);
    if (gy >= 0 && gy < kH2 && gx >= 0 && gx < kH2) {
      const unsigned short* src = (plane ? gfl : gfh) + ((size_t)(gy * kH2 + gx)) * 64 + c8 * 8;
      u = *(const uint4*)src;
    }
    *(uint4*)(Asb + plane * 25920 + p * 144 + c8 * 16) = u;
  }
  __syncthreads();

  const int w = t >> 6, lane = t & 63;
  const int quad = lane >> 4, ml = lane & 15;
  const int abase = (((ml >> 3) * 10) + (ml & 7)) * 144 + quad * 16;
  const int n16base = nb * 16 + w * 4;
  const unsigned int bvoff = (unsigned int)lane * 16u;

  f4v acc[8][4];
#pragma unroll
  for (int i = 0; i < 8; ++i)
#pragma unroll
    for (int j = 0; j < 4; ++j) acc[i][j] = (f4v){0.0f, 0.0f, 0.0f, 0.0f};

#pragma unroll
  for (int kk = 0; kk < 9; ++kk) {
    const int ky = kk / 3, kx = kk % 3;
#pragma unroll
    for (int cs = 0; cs < 2; ++cs) {
      const int kstep = kk * 2 + cs;
      s8v Bh[4], Bl[4];
#pragma unroll
      for (int j = 0; j < 4; ++j) {
        unsigned int off = ((unsigned int)(n16base + j) * 18u + (unsigned int)kstep) * 1024u + bvoff;
        Bh[j] = *(const s8v*)((const char*)wph + off);
        Bl[j] = *(const s8v*)((const char*)wpl + off);
      }
#pragma unroll
      for (int i = 0; i < 8; ++i) {
        const int aoff = ((2 * i + ky) * 10 + kx) * 144 + cs * 64 + abase;
        s8v Ah = *(const s8v*)(Asb + aoff);
        s8v Al = *(const s8v*)(Asb + 25920 + aoff);
#pragma unroll
        for (int j = 0; j < 4; ++j) {
          acc[i][j] = __builtin_amdgcn_mfma_f32_16x16x32_bf16(Ah, Bh[j], acc[i][j], 0, 0, 0);
          acc[i][j] = __builtin_amdgcn_mfma_f32_16x16x32_bf16(Al, Bh[j], acc[i][j], 0, 0, 0);
          acc[i][j] = __builtin_amdgcn_mfma_f32_16x16x32_bf16(Ah, Bl[j], acc[i][j], 0, 0, 0);
        }
      }
    }
  }

  // ---- epilogue via LDS: full-line float4 stores ----
  const int cobase = nb * 256 + w * 64;
  float bj[4];
#pragma unroll
  for (int j = 0; j < 4; ++j) {
    int co = cobase + j * 16 + ml;
    bj[j] = (co < 256) ? coef_b[co] : freq_b[co - 256];
  }
  __syncthreads();               // Asb (A-tile) dead; reuse as staging
  float* Ls = (float*)Asb;       // [32 pixels][268 floats] = 34,304 B
  const int pq = t >> 3;         // pixel slot 0..31 for the read phase
  const int ts = t & 7;
#pragma unroll
  for (int c = 0; c < 4; ++c) {
#pragma unroll
    for (int ii = 0; ii < 2; ++ii) {
      const int i = c * 2 + ii;
#pragma unroll
      for (int j = 0; j < 4; ++j)
#pragma unroll
        for (int reg = 0; reg < 4; ++reg) {
          const int p = ii * 16 + quad * 4 + reg;           // 0..31
          Ls[p * 268 + w * 64 + j * 16 + ml] = acc[i][j][reg] + bj[j];
        }
    }
    __syncthreads();
    const int m = c * 32 + pq;                              // pixel in M-tile
    const int Y = py0 + (m >> 3), X = px0 + (m & 7);
    float* orow = outp + ((size_t)(Y * kH2 + X)) * 512 + nb * 256;
    const float* lrow = Ls + pq * 268;
#pragma unroll
    for (int u = 0; u < 8; ++u)
      *(float4*)(orow + ts * 4 + u * 32) = *(const float4*)(lrow + ts * 4 + u * 32);
    __syncthreads();
  }
}

// ---------------- fused query (ONE image): gather + basis + bf16x3 MFMA MLP ----------------
__global__ __launch_bounds__(256, 2) void k_query_mfma(
    const float* __restrict__ cf, const float* __restrict__ coord,
    const float* __restrict__ cell, const float* __restrict__ phw,
    const unsigned short* __restrict__ wmlp,   // [2][hi/lo][65536]
    const float* __restrict__ b1, const float* __restrict__ b2,
    const float* __restrict__ w3, const float* __restrict__ b3,
    float* __restrict__ out, int q_base) {
  __shared__ __attribute__((aligned(16))) char Xs[2 * 64 * 264 * 2];  // 67,584 B
  constexpr int ROW = 264 * 2;
  constexpr int PLANE = 64 * 264 * 2;
  const int t = threadIdx.x;
  const int q0 = q_base + blockIdx.x * 64;

  {
    const int tq = t >> 2, ts = t & 3;
    const int qg = q0 + tq;
    float gy = coord[(size_t)qg * 2 + 0];
    float gx = coord[(size_t)qg * 2 + 1];
    float fx = ((gx + 1.0f) * 224.0f - 1.0f) * 0.5f;
    float fy = ((gy + 1.0f) * 224.0f - 1.0f) * 0.5f;
    int ix = (int)rintf(fx);
    int iy = (int)rintf(fy);
    bool ok = (ix >= 0) && (ix < 224) && (iy >= 0) && (iy < 224);
    int ixc = min(max(ix, 0), 223);
    int iyc = min(max(iy, 0), 223);
    float m = ok ? 1.0f : 0.0f;
    float qcy = ok ? (-1.0f + (1.0f / 224.0f) + (2.0f / 224.0f) * (float)iyc) : 0.0f;
    float qcx = ok ? (-1.0f + (1.0f / 224.0f) + (2.0f / 224.0f) * (float)ixc) : 0.0f;
    float rel0 = (gy - qcy) * 224.0f;
    float rel1 = (gx - qcx) * 224.0f;
    float rc0 = cell[(size_t)qg * 2 + 0] * 224.0f;
    float rc1 = cell[(size_t)qg * 2 + 1] * 224.0f;
    const float* base = cf + (((size_t)iyc * kH2 + ixc) * 512);
    unsigned short ch_[8], cl_[8], sh_[8], sl_[8];
#pragma unroll
    for (int u = 0; u < 8; ++u) {
      const int k4 = ts * 32 + u * 4;
      float4 clo = *(const float4*)(base + k4);
      float4 chi = *(const float4*)(base + 128 + k4);
      float4 f0 = *(const float4*)(base + 256 + 2 * k4);
      float4 f1 = *(const float4*)(base + 256 + 2 * k4 + 4);
      float fr[8] = {f0.x, f0.y, f0.z, f0.w, f1.x, f1.y, f1.z, f1.w};
      float cl4[4] = {clo.x, clo.y, clo.z, clo.w};
      float ch4[4] = {chi.x, chi.y, chi.z, chi.w};
#pragma unroll
      for (int e = 0; e < 4; ++e) {
        const int k = k4 + e;
        float ph = rc0 * phw[2 * k] + rc1 * phw[2 * k + 1];
        float s = m * (fr[2 * e] * rel0 + fr[2 * e + 1] * rel1) + ph;
        float sv, cv;
        sincospif(s, &sv, &cv);
        float xc = m * cl4[e] * cv;
        float xsn = m * ch4[e] * sv;
        const int sl = (u & 1) * 4 + e;
        unsigned short h1_ = f2bf(xc);
        ch_[sl] = h1_; cl_[sl] = f2bf(xc - bf2f(h1_));
        unsigned short h2_ = f2bf(xsn);
        sh_[sl] = h2_; sl_[sl] = f2bf(xsn - bf2f(h2_));
      }
      if (u & 1) {
        const int kb = ts * 32 + (u - 1) * 4;
        uint4 v;
        v.x = (unsigned)ch_[0] | ((unsigned)ch_[1] << 16);
        v.y = (unsigned)ch_[2] | ((unsigned)ch_[3] << 16);
        v.z = (unsigned)ch_[4] | ((unsigned)ch_[5] << 16);
        v.w = (unsigned)ch_[6] | ((unsigned)ch_[7] << 16);
        *(uint4*)(Xs + tq * ROW + kb * 2) = v;
        v.x = (unsigned)cl_[0] | ((unsigned)cl_[1] << 16);
        v.y = (unsigned)cl_[2] | ((unsigned)cl_[3] << 16);
        v.z = (unsigned)cl_[4] | ((unsigned)cl_[5] << 16);
        v.w = (unsigned)cl_[6] | ((unsigned)cl_[7] << 16);
        *(uint4*)(Xs + PLANE + tq * ROW + kb * 2) = v;
        v.x = (unsigned)sh_[0] | ((unsigned)sh_[1] << 16);
        v.y = (unsigned)sh_[2] | ((unsigned)sh_[3] << 16);
        v.z = (unsigned)sh_[4] | ((unsigned)sh_[5] << 16);
        v.w = (unsigned)sh_[6] | ((unsigned)sh_[7] << 16);
        *(uint4*)(Xs + tq * ROW + (128 + kb) * 2) = v;
        v.x = (unsigned)sl_[0] | ((unsigned)sl_[1] << 16);
        v.y = (unsigned)sl_[2] | ((unsigned)sl_[3] << 16);
        v.z = (unsigned)sl_[4] | ((unsigned)sl_[5] << 16);
        v.w = (unsigned)sl_[6] | ((unsigned)sl_[7] << 16);
        *(uint4*)(Xs + PLANE + tq * ROW + (128 + kb) * 2) = v;
      }
    }
  }
  __syncthreads();

  const int w = t >> 6, lane = t & 63;
  const int quad = lane >> 4, ml = lane & 15;
  const unsigned int bvoff = (unsigned int)lane * 16u;

#pragma unroll
  for (int layer = 0; layer < 2; ++layer) {
    const unsigned short* wb = wmlp + layer * 131072;
    f4v acc[4][4];
#pragma unroll
    for (int i = 0; i < 4; ++i)
#pragma unroll
      for (int j = 0; j < 4; ++j) acc[i][j] = (f4v){0.0f, 0.0f, 0.0f, 0.0f};
#pragma unroll
    for (int kstep = 0; kstep < 8; ++kstep) {
      s8v Bh[4], Bl[4];
#pragma unroll
      for (int j = 0; j < 4; ++j) {
        unsigned int off = (unsigned int)((w * 4 + j) * 8 + kstep) * 1024u + bvoff;
        Bh[j] = *(const s8v*)((const char*)wb + off);
        Bl[j] = *(const s8v*)((const char*)(wb + 65536) + off);
      }
#pragma unroll
      for (int i = 0; i < 4; ++i) {
        const int aoff = (i * 16 + ml) * ROW + (kstep * 32 + quad * 8) * 2;
        s8v Ah = *(const s8v*)(Xs + aoff);
        s8v Al = *(const s8v*)(Xs + PLANE + aoff);
#pragma unroll
        for (int j = 0; j < 4; ++j) {
          acc[i][j] = __builtin_amdgcn_mfma_f32_16x16x32_bf16(Ah, Bh[j], acc[i][j], 0, 0, 0);
          acc[i][j] = __builtin_amdgcn_mfma_f32_16x16x32_bf16(Al, Bh[j], acc[i][j], 0, 0, 0);
          acc[i][j] = __builtin_amdgcn_mfma_f32_16x16x32_bf16(Ah, Bl[j], acc[i][j], 0, 0, 0);
        }
      }
    }
    __syncthreads();
    const float* bs = layer ? b2 : b1;
    float bj[4];
#pragma unroll
    for (int j = 0; j < 4; ++j) bj[j] = bs[w * 64 + j * 16 + ml];
    if (layer == 0) {
#pragma unroll
      for (int i = 0; i < 4; ++i)
#pragma unroll
        for (int j = 0; j < 4; ++j)
#pragma unroll
          for (int reg = 0; reg < 4; ++reg) {
            int m = i * 16 + quad * 4 + reg;
            int n = w * 64 + j * 16 + ml;
            float v = fmaxf(acc[i][j][reg] + bj[j], 0.0f);
            unsigned short hi = f2bf(v);
            unsigned short lo = f2bf(v - bf2f(hi));
            *(unsigned short*)(Xs + m * ROW + n * 2) = hi;
            *(unsigned short*)(Xs + PLANE + m * ROW + n * 2) = lo;
          }
    } else {
#pragma unroll
      for (int i = 0; i < 4; ++i)
#pragma unroll
        for (int j = 0; j < 4; ++j)
#pragma unroll
          for (int reg = 0; reg < 4; ++reg) {
            int m = i * 16 + quad * 4 + reg;
            int n = w * 64 + j * 16 + ml;
            float v = fmaxf(acc[i][j][reg] + bj[j], 0.0f);
            *(float*)(Xs + ((size_t)m * 264 + n) * 4) = v;
          }
    }
    __syncthreads();
  }

  {
    const int tq = t >> 2, ts = t & 3;
    const float* xr = (const float*)(Xs + (size_t)tq * 264 * 4);
    float c0 = 0, c1 = 0, c2 = 0;
    for (int k = ts * 64; k < ts * 64 + 64; ++k) {
      float xv = xr[k];
      c0 += xv * w3[k];
      c1 += xv * w3[256 + k];
      c2 += xv * w3[512 + k];
    }
    c0 += __shfl_down(c0, 2, 4); c0 += __shfl_down(c0, 1, 4);
    c1 += __shfl_down(c1, 2, 4); c1 += __shfl_down(c1, 1, 4);
    c2 += __shfl_down(c2, 2, 4); c2 += __shfl_down(c2, 1, 4);
    if (ts == 0) {
      const int qg = q0 + tq;
      float* o = out + (size_t)qg * 3;
      o[0] = c0 + b3[0];
      o[1] = c1 + b3[1];
      o[2] = c2 + b3[2];
    }
  }
}

// ---------------- launch ----------------
extern "C" void kernel_launch(void* const* d_in, const int* in_sizes, int n_in,
                              void* d_out, int out_size, void* d_ws, size_t ws_size,
                              hipStream_t stream) {
  (void)in_sizes; (void)n_in; (void)out_size; (void)ws_size;
  const float* feat   = (const float*)d_in[0];
  const float* coord  = (const float*)d_in[1];
  const float* cell   = (const float*)d_in[2];
  const float* cls_w1 = (const float*)d_in[3];
  const float* cls_b1 = (const float*)d_in[4];
  const float* cls_w2 = (const float*)d_in[5];
  const float* cls_b2 = (const float*)d_in[6];
  const float* sigx   = (const float*)d_in[7];
  const float* sigy   = (const float*)d_in[8];
  const float* opac   = (const float*)d_in[9];
  const float* rho    = (const float*)d_in[10];
  const float* coef_w = (const float*)d_in[11];
  const float* coef_b = (const float*)d_in[12];
  const float* freq_w = (const float*)d_in[13];
  const float* freq_b = (const float*)d_in[14];
  const float* phw    = (const float*)d_in[15];
  const float* w1     = (const float*)d_in[16];
  const float* b1     = (const float*)d_in[17];
  const float* w2     = (const float*)d_in[18];
  const float* b2     = (const float*)d_in[19];
  const float* w3     = (const float*)d_in[20];
  const float* b3     = (const float*)d_in[21];

  char* ws = (char*)d_ws;
  float* h_buf = (float*)(ws + OFF_H);
  unsigned short* gfh = (unsigned short*)(ws + OFF_GFH);
  unsigned short* gfl = (unsigned short*)(ws + OFF_GFL);
  float* cfb   = (float*)(ws + OFF_CF);
  unsigned short* wph = (unsigned short*)(ws + OFF_WPH);
  unsigned short* wpl = (unsigned short*)(ws + OFF_WPL);
  unsigned short* wmlp = (unsigned short*)(ws + OFF_WMLP);
  float* wsums = (float*)(ws + OFF_WSUM);
  float* wk    = (float*)(ws + OFF_WK);
  float* outp  = (float*)d_out;

  hipLaunchKernelGGL(k_init, dim3(1), dim3(256), 0, stream, wsums);
  hipLaunchKernelGGL(k_prepw, dim3(1152), dim3(256), 0, stream, coef_w, freq_w, wph, wpl);
  hipLaunchKernelGGL(k_prepmlp, dim3(512), dim3(256), 0, stream, w1, w2, wmlp);
  hipLaunchKernelGGL((k_conv3x3<112, 64, 4, true>), dim3(784), dim3(256), 0, stream,
                     feat, cls_w1, cls_b1, cls_w1, cls_b1, h_buf);
  hipLaunchKernelGGL(k_wavg, dim3(196), dim3(256), 0, stream,
                     h_buf, cls_w2, cls_b2, sigx, sigy, opac, rho, wsums);
  hipLaunchKernelGGL(k_finalize, dim3(1), dim3(256), 0, stream, wsums, wk);

  for (int b = 0; b < kB; ++b) {
    const float* feat_b = feat + (size_t)b * 64 * kH1 * kH1;
    hipLaunchKernelGGL(k_splat, dim3(256), dim3(256), 0, stream, feat_b, wk, gfh, gfl);
    hipLaunchKernelGGL(k_conv2_mfma, dim3(784), dim3(256), 0, stream,
                       gfh, gfl, wph, wpl, coef_b, freq_b, cfb);
    hipLaunchKernelGGL(k_query_mfma, dim3(784), dim3(256), 0, stream,
                       cfb, coord, cell, phw, wmlp, b1, b2, w3, b3, outp, b * kQ);
  }
}